// Round 6
// baseline (22384.444 us; speedup 1.0000x reference)
//
#include <hip/hip_runtime.h>
#include <hip/hip_bf16.h>
#include <hip/hip_cooperative_groups.h>
#include <cstddef>

namespace cg = cooperative_groups;

// MatchLSTM round 6: round-5 design with the s_sleep immediate-operand fix.
// Persistent coop kernel, relaxed-flag sync + L2-bypass payload; weights stay
// L2-cached (no acquire/release invalidations on the hot path).
// V=50000, E=300, H=300, C=3, TP=128, TH=64, B=256
#define HDIM 300
#define EDIM 300
#define BATCH 256
#define TPREM 128
#define THYP 64
#define NTHR 256
#define NBLK 304
#define KTT 32

__device__ __forceinline__ float fast_sigm(float x) {
    return 1.f / (1.f + __expf(-x));
}
__device__ __forceinline__ float fast_tanh(float x) {
    float e = __expf(2.f * x);
    return 1.f - 2.f / (e + 1.f);
}
// L2-bypass payload accessors (coherent at MALL, no cache invalidation needed)
__device__ __forceinline__ float gload(const float* p) {
    return __hip_atomic_load(p, __ATOMIC_RELAXED, __HIP_MEMORY_SCOPE_AGENT);
}
__device__ __forceinline__ void gstore(float* p, float v) {
    __hip_atomic_store(p, v, __ATOMIC_RELAXED, __HIP_MEMORY_SCOPE_AGENT);
}

struct Params {
    const int* premise; const int* hypothesis;
    const float* w2v; const float* w_e;
    const float* W_s; const float* W_t; const float* W_m;
    const float* fc_w; const float* fc_b;
    const float* pWih; const float* pWhh; const float* pbih; const float* pbhh;
    const float* hWih; const float* hWhh; const float* hbih; const float* hbhh;
    const float* mWih; const float* mbih; const float* mbhh;
    float* h_s;      // [TP][B][H]   (bypass-written in B, cached-read in D)
    float* h_t_all;  // [TH][B][H]
    float* wshs;     // [TP][B][H] = h_s @ W_s^T  (cached stores, read after grid.sync)
    float* wt_ht;    // [TH][B][H] = h_t @ W_t^T
    float* h_m;      // [B][H]  (bypass)
    float* ab;       // [B][H]  (bypass)
    unsigned* cnt;   // 32 counters, stride-32 uints
    float* out;
};

struct SmemB { float hA[320][34]; float As[KTT][34]; float Bs[KTT][68]; };
struct SmemG { float As[KTT][34]; float Bs[KTT][68]; };
struct SmemA {
    float q[304]; float we[304];
    __align__(16) float hm[304];
    float alpha[TPREM]; float red[16];
};
union Smem { SmemB b; SmemG g; SmemA a; };

// ---------------------------------------------------------------------------
// Relaxed flag sync. arrive: __syncthreads drains all waves' stores, then one
// relaxed device-scope increment. wait: tid0 polls relaxed with escalating
// s_sleep backoff (literal immediates only!).
// ---------------------------------------------------------------------------
__device__ __forceinline__ void arrive(unsigned* slot) {
    __syncthreads();
    if (threadIdx.x == 0)
        __hip_atomic_fetch_add(slot, 1u, __ATOMIC_RELAXED, __HIP_MEMORY_SCOPE_AGENT);
}
__device__ __forceinline__ void wait_ge(unsigned* slot, unsigned target) {
    if (threadIdx.x == 0) {
        int sl = 0; long guard = 0;
        while (__hip_atomic_load(slot, __ATOMIC_RELAXED, __HIP_MEMORY_SCOPE_AGENT) < target) {
            if (sl < 4)       __builtin_amdgcn_s_sleep(1);
            else if (sl < 16) __builtin_amdgcn_s_sleep(8);
            else              __builtin_amdgcn_s_sleep(64);
            ++sl;
            if (++guard > (1L << 16)) break;   // deadlock insurance
        }
    }
    __syncthreads();
}

// ---------------------------------------------------------------------------
// 32x64 tile of G = [A0|A1] @ [W0|W1]^T (round-1 layout). abyp: A0 via gload.
// ---------------------------------------------------------------------------
__device__ __forceinline__ void tile_mm(
    float (&acc)[2][4], Smem& sm,
    const float* A0, int lda0, int K0, bool abyp,
    const float* A1, int lda1, int K1,
    const float* W0, int ld0, const float* W1, int ld1,
    bool gated, int m0, int colbase)
{
    const int tid = threadIdx.x;
    const int K = K0 + K1;
    const int fa_b = tid >> 3;
    const int fa_k0 = (tid & 7) * 4;
    const int fb_c = tid >> 2;
    const int fb_k0 = (tid & 3) * 8;
    int wrow; bool wvalid;
    if (gated) {
        int hh = colbase + (fb_c >> 2);
        wrow = (fb_c & 3) * HDIM + hh;
        wvalid = hh < HDIM;
    } else {
        wrow = colbase + fb_c;
        wvalid = wrow < HDIM;
    }
    const int r = m0 + fa_b;
    const float* a0row = A0 ? A0 + (size_t)r * lda0 : nullptr;
    const float* a1row = A1 ? A1 + (size_t)r * lda1 : nullptr;
    const int pb = tid & 15, hl = tid >> 4;

    for (int kc = 0; kc < K; kc += KTT) {
        #pragma unroll
        for (int u = 0; u < 4; ++u) {
            int kk = fa_k0 + u, k = kc + kk;
            float v = 0.f;
            if (k < K0)      { if (a0row) v = abyp ? gload(&a0row[k]) : a0row[k]; }
            else if (k < K)  { if (a1row) v = a1row[k - K0]; }
            sm.g.As[kk][fa_b] = v;
        }
        #pragma unroll
        for (int u = 0; u < 8; ++u) {
            int kk = fb_k0 + u, k = kc + kk;
            float v = 0.f;
            if (wvalid) {
                if (k < K0)     v = W0[(size_t)wrow * ld0 + k];
                else if (k < K) v = W1[(size_t)wrow * ld1 + (k - K0)];
            }
            sm.g.Bs[kk][fb_c] = v;
        }
        __syncthreads();
        #pragma unroll
        for (int kk = 0; kk < KTT; ++kk) {
            float2 av = *(const float2*)&sm.g.As[kk][pb * 2];
            float4 wv = *(const float4*)&sm.g.Bs[kk][hl * 4];
            acc[0][0] = fmaf(av.x, wv.x, acc[0][0]);
            acc[0][1] = fmaf(av.x, wv.y, acc[0][1]);
            acc[0][2] = fmaf(av.x, wv.z, acc[0][2]);
            acc[0][3] = fmaf(av.x, wv.w, acc[0][3]);
            acc[1][0] = fmaf(av.y, wv.x, acc[1][0]);
            acc[1][1] = fmaf(av.y, wv.y, acc[1][1]);
            acc[1][2] = fmaf(av.y, wv.z, acc[1][2]);
            acc[1][3] = fmaf(av.y, wv.w, acc[1][3]);
        }
        __syncthreads();
    }
}

// 32x64 tile of h @ Wp^T using the already-staged hA (K=300), cached stores.
__device__ void proj_from_hA(Smem& sm, const float* Wp, float* dst,
                             int trow, int b0, int n0)
{
    const int tid = threadIdx.x;
    const int fb_c = tid >> 2, fb_k0 = (tid & 3) * 8;
    const int pb = tid & 15, hl = tid >> 4;
    const int wrow = n0 + fb_c;
    const bool wvalid = wrow < HDIM;
    float acc[2][4] = {};
    for (int kc = 0; kc < HDIM; kc += KTT) {
        #pragma unroll
        for (int u = 0; u < 8; ++u) {
            int kk = fb_k0 + u, k = kc + kk;
            sm.b.Bs[kk][fb_c] = (wvalid && k < HDIM)
                ? Wp[(size_t)wrow * HDIM + k] : 0.f;
        }
        __syncthreads();
        #pragma unroll
        for (int kk = 0; kk < KTT; ++kk) {
            float2 av = *(const float2*)&sm.b.hA[kc + kk][pb * 2];
            float4 wv = *(const float4*)&sm.b.Bs[kk][hl * 4];
            acc[0][0] = fmaf(av.x, wv.x, acc[0][0]);
            acc[0][1] = fmaf(av.x, wv.y, acc[0][1]);
            acc[0][2] = fmaf(av.x, wv.z, acc[0][2]);
            acc[0][3] = fmaf(av.x, wv.w, acc[0][3]);
            acc[1][0] = fmaf(av.y, wv.x, acc[1][0]);
            acc[1][1] = fmaf(av.y, wv.y, acc[1][1]);
            acc[1][2] = fmaf(av.y, wv.z, acc[1][2]);
            acc[1][3] = fmaf(av.y, wv.w, acc[1][3]);
        }
        __syncthreads();
    }
    #pragma unroll
    for (int u = 0; u < 2; ++u) {
        size_t row = (size_t)trow * BATCH + b0 + pb * 2 + u;
        #pragma unroll
        for (int j = 0; j < 4; ++j) {
            int col = n0 + hl * 4 + j;
            if (col < HDIM) dst[row * HDIM + col] = acc[u][j];
        }
    }
}

__device__ __forceinline__ void stage_hA(Smem& sm, const float* hrow_base, int b0) {
    const int tid = threadIdx.x;
    for (int idx = tid; idx < 32 * HDIM; idx += NTHR) {
        int r = idx / HDIM, k = idx - r * HDIM;
        sm.b.hA[k][r] = gload(&hrow_base[(size_t)(b0 + r) * HDIM + k]);
    }
    for (int idx = tid; idx < 20 * 34; idx += NTHR)
        sm.b.hA[300 + idx / 34][idx % 34] = 0.f;   // zero K-pad rows
    __syncthreads();
}

// ---------------------------------------------------------------------------
__global__ __launch_bounds__(NTHR, 2) void match_kernel(Params p) {
    cg::grid_group grid = cg::this_grid();
    __shared__ Smem sm;
    const int blk = blockIdx.x;
    const int tid = threadIdx.x;
    const int pb = tid & 15, hl = tid >> 4;
    const size_t BH = (size_t)BATCH * HDIM;

    // ---- Phase 0: zero h_m (bypass) and counters ----
    for (int i = blk * NTHR + tid; i < (int)BH; i += NBLK * NTHR) gstore(&p.h_m[i], 0.f);
    for (int i = blk * NTHR + tid; i < 32 * 32; i += NBLK * NTHR)
        __hip_atomic_store(&p.cnt[i], 0u, __ATOMIC_RELAXED, __HIP_MEMORY_SCOPE_AGENT);
    grid.sync();   // cg sync #1

    // ---- Phase B: both recurrences, per-group relaxed-flag sync ----
    {
        const bool isP = blk < 152;
        const int idx = isP ? blk : blk - 152;
        const int grp = idx / 19, nt = idx % 19;
        unsigned* gslot = &p.cnt[(isP ? grp : 8 + grp) * 32];
        const int b0 = grp * 32, hh0 = nt * 16;
        const int TSTEPS = isP ? TPREM : THYP;
        const int* toks = isP ? p.premise : p.hypothesis;
        const float* Wih = isP ? p.pWih : p.hWih;
        const float* Whh = isP ? p.pWhh : p.hWhh;
        const float* bihp = isP ? p.pbih : p.hbih;
        const float* bhhp = isP ? p.pbhh : p.hbhh;
        float* hseq = isP ? p.h_s : p.h_t_all;
        const float* Wproj = isP ? p.W_s : p.W_t;
        float* proj = isP ? p.wshs : p.wt_ht;

        const int fa_b = tid >> 3;
        const int fa_k0 = (tid & 7) * 4;
        const int fb_c = tid >> 2;
        const int fb_k0 = (tid & 3) * 8;
        const int whh_l = hh0 + (fb_c >> 2);
        const int wrow = (fb_c & 3) * HDIM + whh_l;
        const bool wvalid = whh_l < HDIM;

        const int hh = hh0 + hl;
        float bi = 0.f, bf = 0.f, bg = 0.f, bo = 0.f;
        if (hh < HDIM) {
            bi = bihp[hh] + bhhp[hh];
            bf = bihp[HDIM + hh] + bhhp[HDIM + hh];
            bg = bihp[2 * HDIM + hh] + bhhp[2 * HDIM + hh];
            bo = bihp[3 * HDIM + hh] + bhhp[3 * HDIM + hh];
        }
        float creg[2] = {0.f, 0.f};

        for (int t = 0; t < TSTEPS; ++t) {
            if (t > 0) {
                wait_ge(gslot, 19u * (unsigned)t);
                stage_hA(sm, hseq + (size_t)(t - 1) * BH, b0);   // bypass loads
            }
            float acc[2][4] = {};
            const float* xrow = p.w2v +
                (size_t)toks[(size_t)t * BATCH + b0 + fa_b] * EDIM;
            // K-part 1: x @ Wih^T (w2v gather, normally cached)
            for (int kc = 0; kc < EDIM; kc += KTT) {
                #pragma unroll
                for (int u = 0; u < 4; ++u) {
                    int kk = fa_k0 + u, k = kc + kk;
                    sm.b.As[kk][fa_b] = (k < EDIM) ? xrow[k] : 0.f;
                }
                #pragma unroll
                for (int u = 0; u < 8; ++u) {
                    int kk = fb_k0 + u, k = kc + kk;
                    sm.b.Bs[kk][fb_c] = (wvalid && k < EDIM)
                        ? Wih[(size_t)wrow * EDIM + k] : 0.f;
                }
                __syncthreads();
                #pragma unroll
                for (int kk = 0; kk < KTT; ++kk) {
                    float2 av = *(const float2*)&sm.b.As[kk][pb * 2];
                    float4 wv = *(const float4*)&sm.b.Bs[kk][hl * 4];
                    acc[0][0] = fmaf(av.x, wv.x, acc[0][0]);
                    acc[0][1] = fmaf(av.x, wv.y, acc[0][1]);
                    acc[0][2] = fmaf(av.x, wv.z, acc[0][2]);
                    acc[0][3] = fmaf(av.x, wv.w, acc[0][3]);
                    acc[1][0] = fmaf(av.y, wv.x, acc[1][0]);
                    acc[1][1] = fmaf(av.y, wv.y, acc[1][1]);
                    acc[1][2] = fmaf(av.y, wv.z, acc[1][2]);
                    acc[1][3] = fmaf(av.y, wv.w, acc[1][3]);
                }
                __syncthreads();
            }
            // K-part 2: h[t-1] @ Whh^T (hA staged once, weights cached)
            if (t > 0) {
                for (int kc = 0; kc < HDIM; kc += KTT) {
                    #pragma unroll
                    for (int u = 0; u < 8; ++u) {
                        int kk = fb_k0 + u, k = kc + kk;
                        sm.b.Bs[kk][fb_c] = (wvalid && k < HDIM)
                            ? Whh[(size_t)wrow * HDIM + k] : 0.f;
                    }
                    __syncthreads();
                    #pragma unroll
                    for (int kk = 0; kk < KTT; ++kk) {
                        float2 av = *(const float2*)&sm.b.hA[kc + kk][pb * 2];
                        float4 wv = *(const float4*)&sm.b.Bs[kk][hl * 4];
                        acc[0][0] = fmaf(av.x, wv.x, acc[0][0]);
                        acc[0][1] = fmaf(av.x, wv.y, acc[0][1]);
                        acc[0][2] = fmaf(av.x, wv.z, acc[0][2]);
                        acc[0][3] = fmaf(av.x, wv.w, acc[0][3]);
                        acc[1][0] = fmaf(av.y, wv.x, acc[1][0]);
                        acc[1][1] = fmaf(av.y, wv.y, acc[1][1]);
                        acc[1][2] = fmaf(av.y, wv.z, acc[1][2]);
                        acc[1][3] = fmaf(av.y, wv.w, acc[1][3]);
                    }
                    __syncthreads();
                }
            }
            // gates + bypass store of h[t]
            if (hh < HDIM) {
                #pragma unroll
                for (int u = 0; u < 2; ++u) {
                    int b = b0 + pb * 2 + u;
                    float gi = fast_sigm(acc[u][0] + bi);
                    float gf = fast_sigm(acc[u][1] + bf);
                    float gg = fast_tanh(acc[u][2] + bg);
                    float go = fast_sigm(acc[u][3] + bo);
                    float c = gf * creg[u] + gi * gg;
                    creg[u] = c;
                    gstore(&hseq[(size_t)t * BH + (size_t)b * HDIM + hh],
                           go * fast_tanh(c));
                }
            }
            arrive(gslot);
            // projection of h[t-1] (reuses hA), off the group's critical path
            if (t > 0) {
                int jj = nt - (5 * (t - 1)) % 19; if (jj < 0) jj += 19;
                if (jj < 5) proj_from_hA(sm, Wproj, proj, t - 1, b0, jj * 64);
            }
        }
        // final projection for t = TSTEPS-1
        {
            int jj = nt - (5 * (TSTEPS - 1)) % 19; if (jj < 0) jj += 19;
            if (jj < 5) {
                wait_ge(gslot, 19u * (unsigned)TSTEPS);
                stage_hA(sm, hseq + (size_t)(TSTEPS - 1) * BH, b0);
                proj_from_hA(sm, Wproj, proj, TSTEPS - 1, b0, jj * 64);
            }
        }
    }
    grid.sync();   // cg sync #2 (full fence: phase-B cached stores -> phase-D reads)

    // ---- Phase D: match loop (blocks 0..255, block = batch element) ----
    if (blk < BATCH) {
        const int b = blk, bt = blk >> 5, j = blk & 31;
        unsigned* cA = &p.cnt[(16 + bt) * 32];
        unsigned* cC = &p.cnt[(24 + bt) * 32];
        const int lane = tid & 63;
        const int wv = tid >> 6;

        for (int k = 0; k < THYP; ++k) {
            wait_ge(cC, 19u * (unsigned)k);   // h_m from prev iter ready

            // q[b] = wt_ht[k][b] + W_m @ h_m[b]
            for (int h = tid; h < HDIM; h += NTHR)
                sm.a.hm[h] = gload(&p.h_m[(size_t)b * HDIM + h]);
            __syncthreads();
            const float* wtrow = p.wt_ht + ((size_t)k * BATCH + b) * HDIM;
            for (int h = tid; h < HDIM; h += NTHR) {
                float a = wtrow[h];
                const float* wr = p.W_m + (size_t)h * HDIM;
                for (int jj = 0; jj < HDIM; jj += 4) {
                    float4 w4 = *(const float4*)&wr[jj];
                    float4 m4 = *(const float4*)&sm.a.hm[jj];
                    a = fmaf(w4.x, m4.x, fmaf(w4.y, m4.y,
                        fmaf(w4.z, m4.z, fmaf(w4.w, m4.w, a))));
                }
                sm.a.q[h] = a;
                sm.a.we[h] = p.w_e[h];
            }
            __syncthreads();

            // e[t] = w_e . tanh(wshs[t,b,:] + q); softmax; ab = sum alpha*h_s
            for (int t = wv; t < TPREM; t += 4) {
                const float* row = p.wshs + ((size_t)t * BATCH + b) * HDIM;
                float pp = 0.f;
                for (int h = lane; h < HDIM; h += 64)
                    pp += sm.a.we[h] * fast_tanh(row[h] + sm.a.q[h]);
                #pragma unroll
                for (int off = 32; off; off >>= 1) pp += __shfl_xor(pp, off, 64);
                if (lane == 0) sm.a.alpha[t] = pp;
            }
            __syncthreads();
            if (wv < 2) {
                float ev = sm.a.alpha[tid];
                float m = ev;
                #pragma unroll
                for (int off = 32; off; off >>= 1) m = fmaxf(m, __shfl_xor(m, off, 64));
                if (lane == 0) sm.a.red[wv] = m;
                __syncthreads();
                float gm = fmaxf(sm.a.red[0], sm.a.red[1]);
                float e = __expf(ev - gm);
                sm.a.alpha[tid] = e;
                float s = e;
                #pragma unroll
                for (int off = 32; off; off >>= 1) s += __shfl_xor(s, off, 64);
                if (lane == 0) sm.a.red[2 + wv] = s;
                __syncthreads();
                sm.a.alpha[tid] *= 1.f / (sm.a.red[2] + sm.a.red[3]);
            } else {
                __syncthreads();
                __syncthreads();
            }
            __syncthreads();
            for (int h = tid; h < HDIM; h += NTHR) {
                const float* hsb = p.h_s + (size_t)b * HDIM + h;
                float a = 0.f;
                #pragma unroll 4
                for (int t = 0; t < TPREM; ++t)
                    a = fmaf(sm.a.alpha[t], hsb[(size_t)t * BH], a);
                gstore(&p.ab[(size_t)b * HDIM + h], a);
            }
            arrive(cA);

            // match cell tiles (19 jobs per bt group), x = [ab | h_t[k]], hx=0
            if (j < 19) {
                wait_ge(cA, 32u * (unsigned)(k + 1));
                float acc[2][4] = {};
                tile_mm(acc, sm,
                        p.ab, HDIM, HDIM, true,
                        p.h_t_all + (size_t)k * BH, HDIM, HDIM,
                        p.mWih, 2 * HDIM, p.mWih + HDIM, 2 * HDIM,
                        true, bt * 32, j * 16);
                int hh = j * 16 + hl;
                if (hh < HDIM) {
                    float bi0 = p.mbih[hh] + p.mbhh[hh];
                    float bi2 = p.mbih[2 * HDIM + hh] + p.mbhh[2 * HDIM + hh];
                    float bi3 = p.mbih[3 * HDIM + hh] + p.mbhh[3 * HDIM + hh];
                    #pragma unroll
                    for (int u = 0; u < 2; ++u) {
                        int bb = bt * 32 + pb * 2 + u;
                        float gi = fast_sigm(acc[u][0] + bi0);
                        float gg = fast_tanh(acc[u][2] + bi2);
                        float go = fast_sigm(acc[u][3] + bi3);
                        gstore(&p.h_m[(size_t)bb * HDIM + hh],
                               go * fast_tanh(gi * gg));
                    }
                }
                arrive(cC);
            }
        }

        // ---- FC for this b ----
        wait_ge(cC, 19u * (unsigned)THYP);
        float p0 = 0.f, p1 = 0.f, p2 = 0.f;
        for (int h = tid; h < HDIM; h += NTHR) {
            float v = gload(&p.h_m[(size_t)b * HDIM + h]);
            p0 = fmaf(v, p.fc_w[h], p0);
            p1 = fmaf(v, p.fc_w[HDIM + h], p1);
            p2 = fmaf(v, p.fc_w[2 * HDIM + h], p2);
        }
        #pragma unroll
        for (int off = 32; off; off >>= 1) {
            p0 += __shfl_xor(p0, off, 64);
            p1 += __shfl_xor(p1, off, 64);
            p2 += __shfl_xor(p2, off, 64);
        }
        __syncthreads();
        if (lane == 0) {
            sm.a.red[wv * 3 + 0] = p0;
            sm.a.red[wv * 3 + 1] = p1;
            sm.a.red[wv * 3 + 2] = p2;
        }
        __syncthreads();
        if (tid == 0) {
            float o0 = 0.f, o1 = 0.f, o2 = 0.f;
            #pragma unroll
            for (int w = 0; w < 4; ++w) {
                o0 += sm.a.red[w * 3 + 0];
                o1 += sm.a.red[w * 3 + 1];
                o2 += sm.a.red[w * 3 + 2];
            }
            p.out[b * 3 + 0] = o0 + p.fc_b[0];
            p.out[b * 3 + 1] = o1 + p.fc_b[1];
            p.out[b * 3 + 2] = o2 + p.fc_b[2];
        }
    }
}

// ===========================================================================
// Fallback path: round-1 multi-kernel implementation (proven correct).
// ===========================================================================
__global__ void k_lstm_gates(
    const int* __restrict__ tok, const float* __restrict__ w2v,
    const float* __restrict__ A0, int K0,
    const float* __restrict__ A1, int K1,
    const float* __restrict__ W0, int ld0,
    const float* __restrict__ W1, int ld1,
    const float* __restrict__ bih, const float* __restrict__ bhh,
    const float* __restrict__ c_in, float* __restrict__ c_out,
    float* __restrict__ h_out)
{
    constexpr int KT = 32;
    __shared__ __align__(16) float As[KT][34];
    __shared__ __align__(16) float Bs[KT][68];

    const int tid = threadIdx.x;
    const int b0 = blockIdx.x * 32;
    const int hh0 = blockIdx.y * 16;
    const int K = K0 + K1;

    const int pb = tid & 15;
    const int hl = tid >> 4;
    const int fa_b = tid >> 3;
    const int fa_k0 = (tid & 7) * 4;
    const int fb_c = tid >> 2;
    const int fb_k0 = (tid & 3) * 8;
    const int fb_hh = hh0 + (fb_c >> 2);
    const int fb_g = fb_c & 3;
    const int fb_row = fb_g * HDIM + fb_hh;
    const bool fb_valid = fb_hh < HDIM;
    const int ga = b0 + fa_b;
    const int tok_b = tok ? tok[ga] : 0;

    float acc[2][4] = {{0.f,0.f,0.f,0.f},{0.f,0.f,0.f,0.f}};

    for (int k0 = 0; k0 < K; k0 += KT) {
        #pragma unroll
        for (int u = 0; u < 4; ++u) {
            int kk = fa_k0 + u;
            int k = k0 + kk;
            float v = 0.f;
            if (k < K0)      v = tok ? w2v[(size_t)tok_b * K0 + k]
                                     : A0[(size_t)ga * K0 + k];
            else if (k < K)  v = A1[(size_t)ga * K1 + (k - K0)];
            As[kk][fa_b] = v;
        }
        #pragma unroll
        for (int u = 0; u < 8; ++u) {
            int kk = fb_k0 + u;
            int k = k0 + kk;
            float v = 0.f;
            if (fb_valid) {
                if (k < K0)     v = W0[(size_t)fb_row * ld0 + k];
                else if (k < K) v = W1[(size_t)fb_row * ld1 + (k - K0)];
            }
            Bs[kk][fb_c] = v;
        }
        __syncthreads();
        #pragma unroll
        for (int kk = 0; kk < KT; ++kk) {
            float2 av = *(const float2*)&As[kk][pb * 2];
            float4 wv = *(const float4*)&Bs[kk][hl * 4];
            acc[0][0] = fmaf(av.x, wv.x, acc[0][0]);
            acc[0][1] = fmaf(av.x, wv.y, acc[0][1]);
            acc[0][2] = fmaf(av.x, wv.z, acc[0][2]);
            acc[0][3] = fmaf(av.x, wv.w, acc[0][3]);
            acc[1][0] = fmaf(av.y, wv.x, acc[1][0]);
            acc[1][1] = fmaf(av.y, wv.y, acc[1][1]);
            acc[1][2] = fmaf(av.y, wv.z, acc[1][2]);
            acc[1][3] = fmaf(av.y, wv.w, acc[1][3]);
        }
        __syncthreads();
    }

    const int hh = hh0 + hl;
    if (hh < HDIM) {
        float bi = bih[hh] + bhh[hh];
        float bf = bih[HDIM + hh] + bhh[HDIM + hh];
        float bg = bih[2 * HDIM + hh] + bhh[2 * HDIM + hh];
        float bo = bih[3 * HDIM + hh] + bhh[3 * HDIM + hh];
        #pragma unroll
        for (int u = 0; u < 2; ++u) {
            int b = b0 + pb * 2 + u;
            float gi = fast_sigm(acc[u][0] + bi);
            float gf = fast_sigm(acc[u][1] + bf);
            float gg = fast_tanh(acc[u][2] + bg);
            float go = fast_sigm(acc[u][3] + bo);
            float c = gf * c_in[(size_t)b * HDIM + hh] + gi * gg;
            c_out[(size_t)b * HDIM + hh] = c;
            h_out[(size_t)b * HDIM + hh] = go * fast_tanh(c);
        }
    }
}

template<int BM, int BN, int TM, int TN, int KT>
__global__ void k_gemm_tn(
    const float* __restrict__ A0, int K0,
    const float* __restrict__ A1, int K1,
    const float* __restrict__ B0, int ldb0,
    const float* __restrict__ B1, int ldb1,
    float* __restrict__ C, int M, int N)
{
    __shared__ __align__(16) float As[KT][BM + 4];
    __shared__ __align__(16) float Bs[KT][BN + 4];
    const int tid = threadIdx.x;
    const int m0 = blockIdx.x * BM;
    const int n0 = blockIdx.y * BN;
    const int K = K0 + K1;
    constexpr int TPM = BM / TM;
    const int tm = tid % TPM;
    const int tn = tid / TPM;

    float acc[TM][TN];
    #pragma unroll
    for (int i = 0; i < TM; ++i)
        #pragma unroll
        for (int j = 0; j < TN; ++j) acc[i][j] = 0.f;

    for (int k0 = 0; k0 < K; k0 += KT) {
        for (int i = tid; i < KT * BM; i += 256) {
            int kk = i % KT, ml = i / KT;
            int m = m0 + ml, k = k0 + kk;
            float v = 0.f;
            if (m < M) {
                if (k < K0)     v = A0[(size_t)m * K0 + k];
                else if (k < K) v = A1[(size_t)m * K1 + (k - K0)];
            }
            As[kk][ml] = v;
        }
        for (int i = tid; i < KT * BN; i += 256) {
            int kk = i % KT, nl = i / KT;
            int n = n0 + nl, k = k0 + kk;
            float v = 0.f;
            if (n < N) {
                if (k < K0)     v = B0[(size_t)n * ldb0 + k];
                else if (k < K) v = B1[(size_t)n * ldb1 + (k - K0)];
            }
            Bs[kk][nl] = v;
        }
        __syncthreads();
        #pragma unroll
        for (int kk = 0; kk < KT; ++kk) {
            float a[TM], w[TN];
            #pragma unroll
            for (int i = 0; i < TM; ++i) a[i] = As[kk][tm * TM + i];
            #pragma unroll
            for (int j = 0; j < TN; ++j) w[j] = Bs[kk][tn * TN + j];
            #pragma unroll
            for (int i = 0; i < TM; ++i)
                #pragma unroll
                for (int j = 0; j < TN; ++j)
                    acc[i][j] = fmaf(a[i], w[j], acc[i][j]);
        }
        __syncthreads();
    }
    #pragma unroll
    for (int i = 0; i < TM; ++i) {
        int m = m0 + tm * TM + i;
        if (m >= M) continue;
        #pragma unroll
        for (int j = 0; j < TN; ++j) {
            int n = n0 + tn * TN + j;
            if (n < N) C[(size_t)m * N + n] = acc[i][j];
        }
    }
}

__global__ void k_attn(const float* __restrict__ ws_hs,
                       const float* __restrict__ h_s,
                       const float* __restrict__ q,
                       const float* __restrict__ w_e,
                       float* __restrict__ a_out)
{
    const int b = blockIdx.x;
    const int tid = threadIdx.x;
    const int lane = tid & 63;
    const int wv = tid >> 6;

    __shared__ float q_s[HDIM];
    __shared__ float we_s[HDIM];
    __shared__ float alpha[TPREM];
    __shared__ float red[4];

    for (int h = tid; h < HDIM; h += 256) {
        q_s[h] = q[(size_t)b * HDIM + h];
        we_s[h] = w_e[h];
    }
    __syncthreads();

    for (int t = wv; t < TPREM; t += 4) {
        const float* row = ws_hs + ((size_t)t * BATCH + b) * HDIM;
        float p = 0.f;
        for (int h = lane; h < HDIM; h += 64)
            p += we_s[h] * fast_tanh(row[h] + q_s[h]);
        #pragma unroll
        for (int off = 32; off; off >>= 1) p += __shfl_xor(p, off, 64);
        if (lane == 0) alpha[t] = p;
    }
    __syncthreads();

    if (wv < 2) {
        float ev = alpha[tid];
        float m = ev;
        #pragma unroll
        for (int off = 32; off; off >>= 1) m = fmaxf(m, __shfl_xor(m, off, 64));
        if (lane == 0) red[wv] = m;
        __syncthreads();
        float gm = fmaxf(red[0], red[1]);
        float e = __expf(ev - gm);
        alpha[tid] = e;
        float s = e;
        #pragma unroll
        for (int off = 32; off; off >>= 1) s += __shfl_xor(s, off, 64);
        if (lane == 0) red[2 + wv] = s;
        __syncthreads();
        alpha[tid] *= 1.f / (red[2] + red[3]);
    } else {
        __syncthreads();
        __syncthreads();
    }
    __syncthreads();

    for (int h = tid; h < HDIM; h += 256) {
        const float* hsb = h_s + (size_t)b * HDIM + h;
        float acc = 0.f;
        #pragma unroll 4
        for (int t = 0; t < TPREM; ++t)
            acc = fmaf(alpha[t], hsb[(size_t)t * BATCH * HDIM], acc);
        a_out[(size_t)b * HDIM + h] = acc;
    }
}

__global__ void k_fc(const float* __restrict__ h_m,
                     const float* __restrict__ fc_w,
                     const float* __restrict__ fc_b,
                     float* __restrict__ out)
{
    const int b = threadIdx.x;
    float a0 = 0.f, a1 = 0.f, a2 = 0.f;
    for (int h = 0; h < HDIM; ++h) {
        float v = h_m[(size_t)b * HDIM + h];
        a0 = fmaf(v, fc_w[h], a0);
        a1 = fmaf(v, fc_w[HDIM + h], a1);
        a2 = fmaf(v, fc_w[2 * HDIM + h], a2);
    }
    out[b * 3 + 0] = a0 + fc_b[0];
    out[b * 3 + 1] = a1 + fc_b[1];
    out[b * 3 + 2] = a2 + fc_b[2];
}

// ===========================================================================
extern "C" void kernel_launch(void* const* d_in, const int* in_sizes, int n_in,
                              void* d_out, int out_size, void* d_ws, size_t ws_size,
                              hipStream_t stream) {
    (void)in_sizes; (void)n_in; (void)out_size;
    const int*   premise    = (const int*)d_in[0];
    const int*   hypothesis = (const int*)d_in[2];
    const float* w2v        = (const float*)d_in[4];
    const float* w_e        = (const float*)d_in[5];
    const float* W_s        = (const float*)d_in[6];
    const float* W_t        = (const float*)d_in[7];
    const float* W_m        = (const float*)d_in[8];
    const float* fc_w       = (const float*)d_in[9];
    const float* fc_b       = (const float*)d_in[10];
    const float* pWih       = (const float*)d_in[11];
    const float* pWhh       = (const float*)d_in[12];
    const float* pbih       = (const float*)d_in[13];
    const float* pbhh       = (const float*)d_in[14];
    const float* hWih       = (const float*)d_in[15];
    const float* hWhh       = (const float*)d_in[16];
    const float* hbih       = (const float*)d_in[17];
    const float* hbhh       = (const float*)d_in[18];
    const float* mWih       = (const float*)d_in[19];
    const float* mbih       = (const float*)d_in[21];
    const float* mbhh       = (const float*)d_in[22];

    const size_t BH = (size_t)BATCH * HDIM;
    const size_t COOP_NEED = 4096 + (386 * BH) * sizeof(float);   // ~118.6 MB

    bool coop_done = false;
    if (ws_size >= COOP_NEED) {
        int maxb = 0;
        hipError_t oe = hipOccupancyMaxActiveBlocksPerMultiprocessor(
            &maxb, match_kernel, NTHR, 0);
        if (oe == hipSuccess && maxb * 256 >= NBLK) {
            Params p;
            p.premise = premise; p.hypothesis = hypothesis;
            p.w2v = w2v; p.w_e = w_e;
            p.W_s = W_s; p.W_t = W_t; p.W_m = W_m;
            p.fc_w = fc_w; p.fc_b = fc_b;
            p.pWih = pWih; p.pWhh = pWhh; p.pbih = pbih; p.pbhh = pbhh;
            p.hWih = hWih; p.hWhh = hWhh; p.hbih = hbih; p.hbhh = hbhh;
            p.mWih = mWih; p.mbih = mbih; p.mbhh = mbhh;

            p.cnt = (unsigned*)d_ws;
            float* f = (float*)((char*)d_ws + 4096);
            p.h_s     = f; f += (size_t)TPREM * BH;
            p.h_t_all = f; f += (size_t)THYP * BH;
            p.wshs    = f; f += (size_t)TPREM * BH;
            p.wt_ht   = f; f += (size_t)THYP * BH;
            p.h_m     = f; f += BH;
            p.ab      = f; f += BH;
            p.out = (float*)d_out;

            void* args[] = { (void*)&p };
            hipError_t le = hipLaunchCooperativeKernel(
                (void*)match_kernel, dim3(NBLK), dim3(NTHR), args, 0, stream);
            coop_done = (le == hipSuccess);
        }
    }
    if (coop_done) return;

    // ---- fallback: round-1 multi-kernel path ----
    float* ws    = (float*)d_ws;
    float* h_s   = ws;
    float* wshs  = h_s + (size_t)TPREM * BH;
    float* zeros = wshs + (size_t)TPREM * BH;
    float* c_p   = zeros + BH;
    float* c_h   = c_p + BH;
    float* c_m   = c_h + BH;
    float* ht0   = c_m + BH;
    float* ht1   = ht0 + BH;
    float* h_m   = ht1 + BH;
    float* qb    = h_m + BH;
    float* ab    = qb + BH;

    (void)hipMemsetAsync(zeros, 0, BH * sizeof(float), stream);
    (void)hipMemsetAsync(c_p,   0, BH * sizeof(float), stream);
    (void)hipMemsetAsync(c_h,   0, BH * sizeof(float), stream);
    (void)hipMemsetAsync(h_m,   0, BH * sizeof(float), stream);

    dim3 gGate(BATCH / 32, (HDIM + 15) / 16);

    for (int t = 0; t < TPREM; ++t) {
        const float* hp = t ? (h_s + (size_t)(t - 1) * BH) : zeros;
        k_lstm_gates<<<gGate, 256, 0, stream>>>(
            premise + (size_t)t * BATCH, w2v, nullptr, EDIM,
            hp, HDIM, pWih, EDIM, pWhh, HDIM,
            pbih, pbhh, c_p, c_p, h_s + (size_t)t * BH);
    }

    k_gemm_tn<64, 64, 4, 4, 16><<<dim3(TPREM * BATCH / 64, (HDIM + 63) / 64), 256, 0, stream>>>(
        h_s, HDIM, nullptr, 0, W_s, HDIM, nullptr, 0, wshs, TPREM * BATCH, HDIM);

    for (int k = 0; k < THYP; ++k) {
        const float* hp = k ? ((k & 1) ? ht0 : ht1) : zeros;
        float* hc = (k & 1) ? ht1 : ht0;
        k_lstm_gates<<<gGate, 256, 0, stream>>>(
            hypothesis + (size_t)k * BATCH, w2v, nullptr, EDIM,
            hp, HDIM, hWih, EDIM, hWhh, HDIM,
            hbih, hbhh, c_h, c_h, hc);
        k_gemm_tn<16, 64, 1, 4, 16><<<dim3(BATCH / 16, (HDIM + 63) / 64), 256, 0, stream>>>(
            hc, HDIM, h_m, HDIM, W_t, HDIM, W_m, HDIM, qb, BATCH, HDIM);
        k_attn<<<BATCH, 256, 0, stream>>>(wshs, h_s, qb, w_e, ab);
        k_lstm_gates<<<gGate, 256, 0, stream>>>(
            nullptr, nullptr, ab, HDIM,
            hc, HDIM, mWih, 2 * HDIM, mWih + HDIM, 2 * HDIM,
            mbih, mbhh, zeros, c_m, h_m);
    }

    k_fc<<<1, BATCH, 0, stream>>>(h_m, fc_w, fc_b, (float*)d_out);
}

// Round 7
// 22327.708 us; speedup vs baseline: 1.0025x; 1.0025x over previous
//
#include <hip/hip_runtime.h>
#include <hip/hip_bf16.h>
#include <hip/hip_cooperative_groups.h>
#include <cstddef>

namespace cg = cooperative_groups;

// MatchLSTM round 7: R6 persistent coop kernel + attention operands stored
// transposed [B][TP][H] in bf16. Phase D reads become contiguous coalesced
// streams (the 5.3 GB strided-fp32 FETCH storm was the real bottleneck).
// V=50000, E=300, H=300, C=3, TP=128, TH=64, B=256
#define HDIM 300
#define EDIM 300
#define BATCH 256
#define TPREM 128
#define THYP 64
#define NTHR 256
#define NBLK 304
#define KTT 32

__device__ __forceinline__ float fast_sigm(float x) {
    return 1.f / (1.f + __expf(-x));
}
__device__ __forceinline__ float fast_tanh(float x) {
    float e = __expf(2.f * x);
    return 1.f - 2.f / (e + 1.f);
}
__device__ __forceinline__ unsigned short f2bf(float f) {
    __hip_bfloat16 h = __float2bfloat16(f);
    return *reinterpret_cast<unsigned short*>(&h);
}
__device__ __forceinline__ float bf2f(unsigned short u) {
    return __uint_as_float((unsigned)u << 16);
}
// L2-bypass payload accessors (coherent at MALL)
__device__ __forceinline__ float gload(const float* p) {
    return __hip_atomic_load(p, __ATOMIC_RELAXED, __HIP_MEMORY_SCOPE_AGENT);
}
__device__ __forceinline__ void gstore(float* p, float v) {
    __hip_atomic_store(p, v, __ATOMIC_RELAXED, __HIP_MEMORY_SCOPE_AGENT);
}

struct Params {
    const int* premise; const int* hypothesis;
    const float* w2v; const float* w_e;
    const float* W_s; const float* W_t; const float* W_m;
    const float* fc_w; const float* fc_b;
    const float* pWih; const float* pWhh; const float* pbih; const float* pbhh;
    const float* hWih; const float* hWhh; const float* hbih; const float* hbhh;
    const float* mWih; const float* mbih; const float* mbhh;
    float* h_s;      // [TP][B][H] fp32 (bypass; recurrence staging)
    float* h_t_all;  // [TH][B][H] fp32 (bypass; match-cell A1, cached read after gsync)
    float* wt_ht;    // [TH][B][H] fp32 = h_t @ W_t^T (cached)
    float* h_m;      // [B][H] (bypass)
    float* ab;       // [B][H] (bypass)
    unsigned short* wshsT;  // [B][TP][H] bf16 = (h_s @ W_s^T)^T  (cached)
    unsigned short* hsT;    // [B][TP][H] bf16 copy of h_s        (cached)
    unsigned* cnt;   // counters, stride-32 uints
    float* out;
};

struct SmemB { float hA[320][34]; float As[KTT][34]; float Bs[KTT][68]; };
struct SmemG { float As[KTT][34]; float Bs[KTT][68]; };
struct SmemA {
    float q[304]; float we[304];
    __align__(16) float hm[304];
    float alpha[TPREM]; float red[16];
    float pa[4][320];
};
union Smem { SmemB b; SmemG g; SmemA a; };

// ---------------------------------------------------------------------------
// Relaxed flag sync (R6-proven).
// ---------------------------------------------------------------------------
__device__ __forceinline__ void arrive(unsigned* slot) {
    __syncthreads();
    if (threadIdx.x == 0)
        __hip_atomic_fetch_add(slot, 1u, __ATOMIC_RELAXED, __HIP_MEMORY_SCOPE_AGENT);
}
__device__ __forceinline__ void wait_ge(unsigned* slot, unsigned target) {
    if (threadIdx.x == 0) {
        int sl = 0; long guard = 0;
        while (__hip_atomic_load(slot, __ATOMIC_RELAXED, __HIP_MEMORY_SCOPE_AGENT) < target) {
            if (sl < 4)       __builtin_amdgcn_s_sleep(1);
            else if (sl < 16) __builtin_amdgcn_s_sleep(8);
            else              __builtin_amdgcn_s_sleep(64);
            ++sl;
            if (++guard > (1L << 16)) break;   // deadlock insurance
        }
    }
    __syncthreads();
}

// ---------------------------------------------------------------------------
// 32x64 tile of G = [A0|A1] @ [W0|W1]^T (round-1 layout). abyp: A0 via gload.
// ---------------------------------------------------------------------------
__device__ __forceinline__ void tile_mm(
    float (&acc)[2][4], Smem& sm,
    const float* A0, int lda0, int K0, bool abyp,
    const float* A1, int lda1, int K1,
    const float* W0, int ld0, const float* W1, int ld1,
    bool gated, int m0, int colbase)
{
    const int tid = threadIdx.x;
    const int K = K0 + K1;
    const int fa_b = tid >> 3;
    const int fa_k0 = (tid & 7) * 4;
    const int fb_c = tid >> 2;
    const int fb_k0 = (tid & 3) * 8;
    int wrow; bool wvalid;
    if (gated) {
        int hh = colbase + (fb_c >> 2);
        wrow = (fb_c & 3) * HDIM + hh;
        wvalid = hh < HDIM;
    } else {
        wrow = colbase + fb_c;
        wvalid = wrow < HDIM;
    }
    const int r = m0 + fa_b;
    const float* a0row = A0 ? A0 + (size_t)r * lda0 : nullptr;
    const float* a1row = A1 ? A1 + (size_t)r * lda1 : nullptr;
    const int pb = tid & 15, hl = tid >> 4;

    for (int kc = 0; kc < K; kc += KTT) {
        #pragma unroll
        for (int u = 0; u < 4; ++u) {
            int kk = fa_k0 + u, k = kc + kk;
            float v = 0.f;
            if (k < K0)      { if (a0row) v = abyp ? gload(&a0row[k]) : a0row[k]; }
            else if (k < K)  { if (a1row) v = a1row[k - K0]; }
            sm.g.As[kk][fa_b] = v;
        }
        #pragma unroll
        for (int u = 0; u < 8; ++u) {
            int kk = fb_k0 + u, k = kc + kk;
            float v = 0.f;
            if (wvalid) {
                if (k < K0)     v = W0[(size_t)wrow * ld0 + k];
                else if (k < K) v = W1[(size_t)wrow * ld1 + (k - K0)];
            }
            sm.g.Bs[kk][fb_c] = v;
        }
        __syncthreads();
        #pragma unroll
        for (int kk = 0; kk < KTT; ++kk) {
            float2 av = *(const float2*)&sm.g.As[kk][pb * 2];
            float4 wv = *(const float4*)&sm.g.Bs[kk][hl * 4];
            acc[0][0] = fmaf(av.x, wv.x, acc[0][0]);
            acc[0][1] = fmaf(av.x, wv.y, acc[0][1]);
            acc[0][2] = fmaf(av.x, wv.z, acc[0][2]);
            acc[0][3] = fmaf(av.x, wv.w, acc[0][3]);
            acc[1][0] = fmaf(av.y, wv.x, acc[1][0]);
            acc[1][1] = fmaf(av.y, wv.y, acc[1][1]);
            acc[1][2] = fmaf(av.y, wv.z, acc[1][2]);
            acc[1][3] = fmaf(av.y, wv.w, acc[1][3]);
        }
        __syncthreads();
    }
}

// 32x64 tile of h @ Wp^T using the already-staged hA (K=300).
// Premise (toBf16T): store bf16 TRANSPOSED [b][t][col]. Hyp: fp32 [t][b][col].
__device__ void proj_from_hA(Smem& sm, const float* Wp,
                             float* dstf, unsigned short* dstb, bool toBf16T,
                             int trow, int b0, int n0)
{
    const int tid = threadIdx.x;
    const int fb_c = tid >> 2, fb_k0 = (tid & 3) * 8;
    const int pb = tid & 15, hl = tid >> 4;
    const int wrow = n0 + fb_c;
    const bool wvalid = wrow < HDIM;
    float acc[2][4] = {};
    for (int kc = 0; kc < HDIM; kc += KTT) {
        #pragma unroll
        for (int u = 0; u < 8; ++u) {
            int kk = fb_k0 + u, k = kc + kk;
            sm.b.Bs[kk][fb_c] = (wvalid && k < HDIM)
                ? Wp[(size_t)wrow * HDIM + k] : 0.f;
        }
        __syncthreads();
        #pragma unroll
        for (int kk = 0; kk < KTT; ++kk) {
            float2 av = *(const float2*)&sm.b.hA[kc + kk][pb * 2];
            float4 wv = *(const float4*)&sm.b.Bs[kk][hl * 4];
            acc[0][0] = fmaf(av.x, wv.x, acc[0][0]);
            acc[0][1] = fmaf(av.x, wv.y, acc[0][1]);
            acc[0][2] = fmaf(av.x, wv.z, acc[0][2]);
            acc[0][3] = fmaf(av.x, wv.w, acc[0][3]);
            acc[1][0] = fmaf(av.y, wv.x, acc[1][0]);
            acc[1][1] = fmaf(av.y, wv.y, acc[1][1]);
            acc[1][2] = fmaf(av.y, wv.z, acc[1][2]);
            acc[1][3] = fmaf(av.y, wv.w, acc[1][3]);
        }
        __syncthreads();
    }
    const int col = n0 + hl * 4;
    #pragma unroll
    for (int u = 0; u < 2; ++u) {
        const int brow = b0 + pb * 2 + u;
        if (toBf16T) {
            if (col < HDIM) {   // col multiple of 4, col<=296 -> col+3<300
                ushort4 v4;
                v4.x = f2bf(acc[u][0]); v4.y = f2bf(acc[u][1]);
                v4.z = f2bf(acc[u][2]); v4.w = f2bf(acc[u][3]);
                *reinterpret_cast<ushort4*>(
                    &dstb[((size_t)brow * TPREM + trow) * HDIM + col]) = v4;
            }
        } else {
            size_t row = (size_t)trow * BATCH + brow;
            #pragma unroll
            for (int j = 0; j < 4; ++j) {
                int c = col + j;
                if (c < HDIM) dstf[row * HDIM + c] = acc[u][j];
            }
        }
    }
}

__device__ __forceinline__ void stage_hA(Smem& sm, const float* hrow_base, int b0) {
    const int tid = threadIdx.x;
    for (int idx = tid; idx < 32 * HDIM; idx += NTHR) {
        int r = idx / HDIM, k = idx - r * HDIM;
        sm.b.hA[k][r] = gload(&hrow_base[(size_t)(b0 + r) * HDIM + k]);
    }
    for (int idx = tid; idx < 20 * 34; idx += NTHR)
        sm.b.hA[300 + idx / 34][idx % 34] = 0.f;
    __syncthreads();
}

// ---------------------------------------------------------------------------
__global__ __launch_bounds__(NTHR, 2) void match_kernel(Params p) {
    cg::grid_group grid = cg::this_grid();
    __shared__ Smem sm;
    const int blk = blockIdx.x;
    const int tid = threadIdx.x;
    const int pb = tid & 15, hl = tid >> 4;
    const size_t BH = (size_t)BATCH * HDIM;

    // ---- Phase 0 ----
    for (int i = blk * NTHR + tid; i < (int)BH; i += NBLK * NTHR) gstore(&p.h_m[i], 0.f);
    for (int i = blk * NTHR + tid; i < 32 * 32; i += NBLK * NTHR)
        __hip_atomic_store(&p.cnt[i], 0u, __ATOMIC_RELAXED, __HIP_MEMORY_SCOPE_AGENT);
    grid.sync();   // cg sync #1

    // ---- Phase B: both recurrences, per-group relaxed-flag sync (R6-proven) ----
    {
        const bool isP = blk < 152;
        const int idx = isP ? blk : blk - 152;
        const int grp = idx / 19, nt = idx % 19;
        unsigned* gslot = &p.cnt[(isP ? grp : 8 + grp) * 32];
        const int b0 = grp * 32, hh0 = nt * 16;
        const int TSTEPS = isP ? TPREM : THYP;
        const int* toks = isP ? p.premise : p.hypothesis;
        const float* Wih = isP ? p.pWih : p.hWih;
        const float* Whh = isP ? p.pWhh : p.hWhh;
        const float* bihp = isP ? p.pbih : p.hbih;
        const float* bhhp = isP ? p.pbhh : p.hbhh;
        float* hseq = isP ? p.h_s : p.h_t_all;
        const float* Wproj = isP ? p.W_s : p.W_t;

        const int fa_b = tid >> 3;
        const int fa_k0 = (tid & 7) * 4;
        const int fb_c = tid >> 2;
        const int fb_k0 = (tid & 3) * 8;
        const int whh_l = hh0 + (fb_c >> 2);
        const int wrow = (fb_c & 3) * HDIM + whh_l;
        const bool wvalid = whh_l < HDIM;

        const int hh = hh0 + hl;
        float bi = 0.f, bf = 0.f, bg = 0.f, bo = 0.f;
        if (hh < HDIM) {
            bi = bihp[hh] + bhhp[hh];
            bf = bihp[HDIM + hh] + bhhp[HDIM + hh];
            bg = bihp[2 * HDIM + hh] + bhhp[2 * HDIM + hh];
            bo = bihp[3 * HDIM + hh] + bhhp[3 * HDIM + hh];
        }
        float creg[2] = {0.f, 0.f};

        for (int t = 0; t < TSTEPS; ++t) {
            if (t > 0) {
                wait_ge(gslot, 19u * (unsigned)t);
                stage_hA(sm, hseq + (size_t)(t - 1) * BH, b0);
            }
            float acc[2][4] = {};
            const float* xrow = p.w2v +
                (size_t)toks[(size_t)t * BATCH + b0 + fa_b] * EDIM;
            // K-part 1: x @ Wih^T
            for (int kc = 0; kc < EDIM; kc += KTT) {
                #pragma unroll
                for (int u = 0; u < 4; ++u) {
                    int kk = fa_k0 + u, k = kc + kk;
                    sm.b.As[kk][fa_b] = (k < EDIM) ? xrow[k] : 0.f;
                }
                #pragma unroll
                for (int u = 0; u < 8; ++u) {
                    int kk = fb_k0 + u, k = kc + kk;
                    sm.b.Bs[kk][fb_c] = (wvalid && k < EDIM)
                        ? Wih[(size_t)wrow * EDIM + k] : 0.f;
                }
                __syncthreads();
                #pragma unroll
                for (int kk = 0; kk < KTT; ++kk) {
                    float2 av = *(const float2*)&sm.b.As[kk][pb * 2];
                    float4 wv = *(const float4*)&sm.b.Bs[kk][hl * 4];
                    acc[0][0] = fmaf(av.x, wv.x, acc[0][0]);
                    acc[0][1] = fmaf(av.x, wv.y, acc[0][1]);
                    acc[0][2] = fmaf(av.x, wv.z, acc[0][2]);
                    acc[0][3] = fmaf(av.x, wv.w, acc[0][3]);
                    acc[1][0] = fmaf(av.y, wv.x, acc[1][0]);
                    acc[1][1] = fmaf(av.y, wv.y, acc[1][1]);
                    acc[1][2] = fmaf(av.y, wv.z, acc[1][2]);
                    acc[1][3] = fmaf(av.y, wv.w, acc[1][3]);
                }
                __syncthreads();
            }
            // K-part 2: h[t-1] @ Whh^T
            if (t > 0) {
                for (int kc = 0; kc < HDIM; kc += KTT) {
                    #pragma unroll
                    for (int u = 0; u < 8; ++u) {
                        int kk = fb_k0 + u, k = kc + kk;
                        sm.b.Bs[kk][fb_c] = (wvalid && k < HDIM)
                            ? Whh[(size_t)wrow * HDIM + k] : 0.f;
                    }
                    __syncthreads();
                    #pragma unroll
                    for (int kk = 0; kk < KTT; ++kk) {
                        float2 av = *(const float2*)&sm.b.hA[kc + kk][pb * 2];
                        float4 wv = *(const float4*)&sm.b.Bs[kk][hl * 4];
                        acc[0][0] = fmaf(av.x, wv.x, acc[0][0]);
                        acc[0][1] = fmaf(av.x, wv.y, acc[0][1]);
                        acc[0][2] = fmaf(av.x, wv.z, acc[0][2]);
                        acc[0][3] = fmaf(av.x, wv.w, acc[0][3]);
                        acc[1][0] = fmaf(av.y, wv.x, acc[1][0]);
                        acc[1][1] = fmaf(av.y, wv.y, acc[1][1]);
                        acc[1][2] = fmaf(av.y, wv.z, acc[1][2]);
                        acc[1][3] = fmaf(av.y, wv.w, acc[1][3]);
                    }
                    __syncthreads();
                }
            }
            // gates + bypass store of h[t] (+ bf16 transposed copy for PV, premise)
            if (hh < HDIM) {
                #pragma unroll
                for (int u = 0; u < 2; ++u) {
                    int b = b0 + pb * 2 + u;
                    float gi = fast_sigm(acc[u][0] + bi);
                    float gf = fast_sigm(acc[u][1] + bf);
                    float gg = fast_tanh(acc[u][2] + bg);
                    float go = fast_sigm(acc[u][3] + bo);
                    float c = gf * creg[u] + gi * gg;
                    creg[u] = c;
                    float hval = go * fast_tanh(c);
                    gstore(&hseq[(size_t)t * BH + (size_t)b * HDIM + hh], hval);
                    if (isP)
                        p.hsT[((size_t)b * TPREM + t) * HDIM + hh] = f2bf(hval);
                }
            }
            arrive(gslot);
            if (t > 0) {
                int jj = nt - (5 * (t - 1)) % 19; if (jj < 0) jj += 19;
                if (jj < 5)
                    proj_from_hA(sm, Wproj, p.wt_ht, p.wshsT, isP,
                                 t - 1, b0, jj * 64);
            }
        }
        {
            int jj = nt - (5 * (TSTEPS - 1)) % 19; if (jj < 0) jj += 19;
            if (jj < 5) {
                wait_ge(gslot, 19u * (unsigned)TSTEPS);
                stage_hA(sm, hseq + (size_t)(TSTEPS - 1) * BH, b0);
                proj_from_hA(sm, Wproj, p.wt_ht, p.wshsT, isP,
                             TSTEPS - 1, b0, jj * 64);
            }
        }
    }
    grid.sync();   // cg sync #2 (fences phase-B cached stores for phase D)

    // ---- Phase D: match loop (blocks 0..255, block = batch element) ----
    if (blk < BATCH) {
        const int b = blk, bt = blk >> 5, j = blk & 31;
        unsigned* cA = &p.cnt[(16 + bt) * 32];
        unsigned* cC = &p.cnt[(24 + bt) * 32];
        const int lane = tid & 63;
        const int wv = tid >> 6;
        const unsigned short* wsb = p.wshsT + (size_t)b * TPREM * HDIM;
        const unsigned short* hsb = p.hsT   + (size_t)b * TPREM * HDIM;

        for (int k = 0; k < THYP; ++k) {
            wait_ge(cC, 19u * (unsigned)k);

            // q[b] = wt_ht[k][b] + W_m @ h_m[b]
            for (int h = tid; h < HDIM; h += NTHR)
                sm.a.hm[h] = gload(&p.h_m[(size_t)b * HDIM + h]);
            __syncthreads();
            const float* wtrow = p.wt_ht + ((size_t)k * BATCH + b) * HDIM;
            for (int h = tid; h < HDIM; h += NTHR) {
                float a = wtrow[h];
                const float* wr = p.W_m + (size_t)h * HDIM;
                for (int jj = 0; jj < HDIM; jj += 4) {
                    float4 w4 = *(const float4*)&wr[jj];
                    float4 m4 = *(const float4*)&sm.a.hm[jj];
                    a = fmaf(w4.x, m4.x, fmaf(w4.y, m4.y,
                        fmaf(w4.z, m4.z, fmaf(w4.w, m4.w, a))));
                }
                sm.a.q[h] = a;
                sm.a.we[h] = p.w_e[h];
            }
            __syncthreads();

            // e-pass: contiguous bf16 rows, lane-stride-1 coalesced loads
            #pragma unroll 2
            for (int t = wv; t < TPREM; t += 4) {
                const unsigned short* row = wsb + (size_t)t * HDIM;
                float pp = 0.f;
                #pragma unroll
                for (int i = 0; i < 5; ++i) {
                    int h = lane + 64 * i;
                    if (h < HDIM)
                        pp += sm.a.we[h] * fast_tanh(bf2f(row[h]) + sm.a.q[h]);
                }
                #pragma unroll
                for (int off = 32; off; off >>= 1) pp += __shfl_xor(pp, off, 64);
                if (lane == 0) sm.a.alpha[t] = pp;
            }
            __syncthreads();
            if (wv < 2) {
                float ev = sm.a.alpha[tid];
                float m = ev;
                #pragma unroll
                for (int off = 32; off; off >>= 1) m = fmaxf(m, __shfl_xor(m, off, 64));
                if (lane == 0) sm.a.red[wv] = m;
                __syncthreads();
                float gm = fmaxf(sm.a.red[0], sm.a.red[1]);
                float e = __expf(ev - gm);
                sm.a.alpha[tid] = e;
                float s = e;
                #pragma unroll
                for (int off = 32; off; off >>= 1) s += __shfl_xor(s, off, 64);
                if (lane == 0) sm.a.red[2 + wv] = s;
                __syncthreads();
                sm.a.alpha[tid] *= 1.f / (sm.a.red[2] + sm.a.red[3]);
            } else {
                __syncthreads();
                __syncthreads();
            }
            __syncthreads();

            // PV: per-wave register accumulators over h = lane + 64i
            {
                float a0 = 0.f, a1 = 0.f, a2 = 0.f, a3 = 0.f, a4 = 0.f;
                #pragma unroll 2
                for (int t = wv; t < TPREM; t += 4) {
                    float w = sm.a.alpha[t];
                    const unsigned short* row = hsb + (size_t)t * HDIM;
                    a0 = fmaf(w, bf2f(row[lane]), a0);
                    a1 = fmaf(w, bf2f(row[lane + 64]), a1);
                    a2 = fmaf(w, bf2f(row[lane + 128]), a2);
                    a3 = fmaf(w, bf2f(row[lane + 192]), a3);
                    if (lane + 256 < HDIM) a4 = fmaf(w, bf2f(row[lane + 256]), a4);
                }
                sm.a.pa[wv][lane] = a0;
                sm.a.pa[wv][lane + 64] = a1;
                sm.a.pa[wv][lane + 128] = a2;
                sm.a.pa[wv][lane + 192] = a3;
                if (lane + 256 < 320) sm.a.pa[wv][lane + 256] = a4;
                __syncthreads();
                for (int h = tid; h < HDIM; h += NTHR)
                    gstore(&p.ab[(size_t)b * HDIM + h],
                           sm.a.pa[0][h] + sm.a.pa[1][h] + sm.a.pa[2][h] + sm.a.pa[3][h]);
            }
            arrive(cA);

            // match cell tiles (19 jobs per bt group), x = [ab | h_t[k]], hx=0
            if (j < 19) {
                wait_ge(cA, 32u * (unsigned)(k + 1));
                float acc[2][4] = {};
                tile_mm(acc, sm,
                        p.ab, HDIM, HDIM, true,
                        p.h_t_all + (size_t)k * BH, HDIM, HDIM,
                        p.mWih, 2 * HDIM, p.mWih + HDIM, 2 * HDIM,
                        true, bt * 32, j * 16);
                int hh = j * 16 + hl;
                if (hh < HDIM) {
                    float bi0 = p.mbih[hh] + p.mbhh[hh];
                    float bi2 = p.mbih[2 * HDIM + hh] + p.mbhh[2 * HDIM + hh];
                    float bi3 = p.mbih[3 * HDIM + hh] + p.mbhh[3 * HDIM + hh];
                    #pragma unroll
                    for (int u = 0; u < 2; ++u) {
                        int bb = bt * 32 + pb * 2 + u;
                        float gi = fast_sigm(acc[u][0] + bi0);
                        float gg = fast_tanh(acc[u][2] + bi2);
                        float go = fast_sigm(acc[u][3] + bi3);
                        gstore(&p.h_m[(size_t)bb * HDIM + hh],
                               go * fast_tanh(gi * gg));
                    }
                }
                arrive(cC);
            }
        }

        // ---- FC ----
        wait_ge(cC, 19u * (unsigned)THYP);
        float p0 = 0.f, p1 = 0.f, p2 = 0.f;
        for (int h = tid; h < HDIM; h += NTHR) {
            float v = gload(&p.h_m[(size_t)b * HDIM + h]);
            p0 = fmaf(v, p.fc_w[h], p0);
            p1 = fmaf(v, p.fc_w[HDIM + h], p1);
            p2 = fmaf(v, p.fc_w[2 * HDIM + h], p2);
        }
        #pragma unroll
        for (int off = 32; off; off >>= 1) {
            p0 += __shfl_xor(p0, off, 64);
            p1 += __shfl_xor(p1, off, 64);
            p2 += __shfl_xor(p2, off, 64);
        }
        __syncthreads();
        if (lane == 0) {
            sm.a.red[wv * 3 + 0] = p0;
            sm.a.red[wv * 3 + 1] = p1;
            sm.a.red[wv * 3 + 2] = p2;
        }
        __syncthreads();
        if (tid == 0) {
            float o0 = 0.f, o1 = 0.f, o2 = 0.f;
            #pragma unroll
            for (int w = 0; w < 4; ++w) {
                o0 += sm.a.red[w * 3 + 0];
                o1 += sm.a.red[w * 3 + 1];
                o2 += sm.a.red[w * 3 + 2];
            }
            p.out[b * 3 + 0] = o0 + p.fc_b[0];
            p.out[b * 3 + 1] = o1 + p.fc_b[1];
            p.out[b * 3 + 2] = o2 + p.fc_b[2];
        }
    }
}

// ===========================================================================
// Fallback path: round-1 multi-kernel implementation (proven correct).
// ===========================================================================
__global__ void k_lstm_gates(
    const int* __restrict__ tok, const float* __restrict__ w2v,
    const float* __restrict__ A0, int K0,
    const float* __restrict__ A1, int K1,
    const float* __restrict__ W0, int ld0,
    const float* __restrict__ W1, int ld1,
    const float* __restrict__ bih, const float* __restrict__ bhh,
    const float* __restrict__ c_in, float* __restrict__ c_out,
    float* __restrict__ h_out)
{
    constexpr int KT = 32;
    __shared__ __align__(16) float As[KT][34];
    __shared__ __align__(16) float Bs[KT][68];

    const int tid = threadIdx.x;
    const int b0 = blockIdx.x * 32;
    const int hh0 = blockIdx.y * 16;
    const int K = K0 + K1;

    const int pb = tid & 15;
    const int hl = tid >> 4;
    const int fa_b = tid >> 3;
    const int fa_k0 = (tid & 7) * 4;
    const int fb_c = tid >> 2;
    const int fb_k0 = (tid & 3) * 8;
    const int fb_hh = hh0 + (fb_c >> 2);
    const int fb_g = fb_c & 3;
    const int fb_row = fb_g * HDIM + fb_hh;
    const bool fb_valid = fb_hh < HDIM;
    const int ga = b0 + fa_b;
    const int tok_b = tok ? tok[ga] : 0;

    float acc[2][4] = {{0.f,0.f,0.f,0.f},{0.f,0.f,0.f,0.f}};

    for (int k0 = 0; k0 < K; k0 += KT) {
        #pragma unroll
        for (int u = 0; u < 4; ++u) {
            int kk = fa_k0 + u;
            int k = k0 + kk;
            float v = 0.f;
            if (k < K0)      v = tok ? w2v[(size_t)tok_b * K0 + k]
                                     : A0[(size_t)ga * K0 + k];
            else if (k < K)  v = A1[(size_t)ga * K1 + (k - K0)];
            As[kk][fa_b] = v;
        }
        #pragma unroll
        for (int u = 0; u < 8; ++u) {
            int kk = fb_k0 + u;
            int k = k0 + kk;
            float v = 0.f;
            if (fb_valid) {
                if (k < K0)     v = W0[(size_t)fb_row * ld0 + k];
                else if (k < K) v = W1[(size_t)fb_row * ld1 + (k - K0)];
            }
            Bs[kk][fb_c] = v;
        }
        __syncthreads();
        #pragma unroll
        for (int kk = 0; kk < KT; ++kk) {
            float2 av = *(const float2*)&As[kk][pb * 2];
            float4 wv = *(const float4*)&Bs[kk][hl * 4];
            acc[0][0] = fmaf(av.x, wv.x, acc[0][0]);
            acc[0][1] = fmaf(av.x, wv.y, acc[0][1]);
            acc[0][2] = fmaf(av.x, wv.z, acc[0][2]);
            acc[0][3] = fmaf(av.x, wv.w, acc[0][3]);
            acc[1][0] = fmaf(av.y, wv.x, acc[1][0]);
            acc[1][1] = fmaf(av.y, wv.y, acc[1][1]);
            acc[1][2] = fmaf(av.y, wv.z, acc[1][2]);
            acc[1][3] = fmaf(av.y, wv.w, acc[1][3]);
        }
        __syncthreads();
    }

    const int hh = hh0 + hl;
    if (hh < HDIM) {
        float bi = bih[hh] + bhh[hh];
        float bf = bih[HDIM + hh] + bhh[HDIM + hh];
        float bg = bih[2 * HDIM + hh] + bhh[2 * HDIM + hh];
        float bo = bih[3 * HDIM + hh] + bhh[3 * HDIM + hh];
        #pragma unroll
        for (int u = 0; u < 2; ++u) {
            int b = b0 + pb * 2 + u;
            float gi = fast_sigm(acc[u][0] + bi);
            float gf = fast_sigm(acc[u][1] + bf);
            float gg = fast_tanh(acc[u][2] + bg);
            float go = fast_sigm(acc[u][3] + bo);
            float c = gf * c_in[(size_t)b * HDIM + hh] + gi * gg;
            c_out[(size_t)b * HDIM + hh] = c;
            h_out[(size_t)b * HDIM + hh] = go * fast_tanh(c);
        }
    }
}

template<int BM, int BN, int TM, int TN, int KT>
__global__ void k_gemm_tn(
    const float* __restrict__ A0, int K0,
    const float* __restrict__ A1, int K1,
    const float* __restrict__ B0, int ldb0,
    const float* __restrict__ B1, int ldb1,
    float* __restrict__ C, int M, int N)
{
    __shared__ __align__(16) float As[KT][BM + 4];
    __shared__ __align__(16) float Bs[KT][BN + 4];
    const int tid = threadIdx.x;
    const int m0 = blockIdx.x * BM;
    const int n0 = blockIdx.y * BN;
    const int K = K0 + K1;
    constexpr int TPM = BM / TM;
    const int tm = tid % TPM;
    const int tn = tid / TPM;

    float acc[TM][TN];
    #pragma unroll
    for (int i = 0; i < TM; ++i)
        #pragma unroll
        for (int j = 0; j < TN; ++j) acc[i][j] = 0.f;

    for (int k0 = 0; k0 < K; k0 += KT) {
        for (int i = tid; i < KT * BM; i += 256) {
            int kk = i % KT, ml = i / KT;
            int m = m0 + ml, k = k0 + kk;
            float v = 0.f;
            if (m < M) {
                if (k < K0)     v = A0[(size_t)m * K0 + k];
                else if (k < K) v = A1[(size_t)m * K1 + (k - K0)];
            }
            As[kk][ml] = v;
        }
        for (int i = tid; i < KT * BN; i += 256) {
            int kk = i % KT, nl = i / KT;
            int n = n0 + nl, k = k0 + kk;
            float v = 0.f;
            if (n < N) {
                if (k < K0)     v = B0[(size_t)n * ldb0 + k];
                else if (k < K) v = B1[(size_t)n * ldb1 + (k - K0)];
            }
            Bs[kk][nl] = v;
        }
        __syncthreads();
        #pragma unroll
        for (int kk = 0; kk < KT; ++kk) {
            float a[TM], w[TN];
            #pragma unroll
            for (int i = 0; i < TM; ++i) a[i] = As[kk][tm * TM + i];
            #pragma unroll
            for (int j = 0; j < TN; ++j) w[j] = Bs[kk][tn * TN + j];
            #pragma unroll
            for (int i = 0; i < TM; ++i)
                #pragma unroll
                for (int j = 0; j < TN; ++j)
                    acc[i][j] = fmaf(a[i], w[j], acc[i][j]);
        }
        __syncthreads();
    }
    #pragma unroll
    for (int i = 0; i < TM; ++i) {
        int m = m0 + tm * TM + i;
        if (m >= M) continue;
        #pragma unroll
        for (int j = 0; j < TN; ++j) {
            int n = n0 + tn * TN + j;
            if (n < N) C[(size_t)m * N + n] = acc[i][j];
        }
    }
}

__global__ void k_attn(const float* __restrict__ ws_hs,
                       const float* __restrict__ h_s,
                       const float* __restrict__ q,
                       const float* __restrict__ w_e,
                       float* __restrict__ a_out)
{
    const int b = blockIdx.x;
    const int tid = threadIdx.x;
    const int lane = tid & 63;
    const int wv = tid >> 6;

    __shared__ float q_s[HDIM];
    __shared__ float we_s[HDIM];
    __shared__ float alpha[TPREM];
    __shared__ float red[4];

    for (int h = tid; h < HDIM; h += 256) {
        q_s[h] = q[(size_t)b * HDIM + h];
        we_s[h] = w_e[h];
    }
    __syncthreads();

    for (int t = wv; t < TPREM; t += 4) {
        const float* row = ws_hs + ((size_t)t * BATCH + b) * HDIM;
        float p = 0.f;
        for (int h = lane; h < HDIM; h += 64)
            p += we_s[h] * fast_tanh(row[h] + q_s[h]);
        #pragma unroll
        for (int off = 32; off; off >>= 1) p += __shfl_xor(p, off, 64);
        if (lane == 0) alpha[t] = p;
    }
    __syncthreads();

    if (wv < 2) {
        float ev = alpha[tid];
        float m = ev;
        #pragma unroll
        for (int off = 32; off; off >>= 1) m = fmaxf(m, __shfl_xor(m, off, 64));
        if (lane == 0) red[wv] = m;
        __syncthreads();
        float gm = fmaxf(red[0], red[1]);
        float e = __expf(ev - gm);
        alpha[tid] = e;
        float s = e;
        #pragma unroll
        for (int off = 32; off; off >>= 1) s += __shfl_xor(s, off, 64);
        if (lane == 0) red[2 + wv] = s;
        __syncthreads();
        alpha[tid] *= 1.f / (red[2] + red[3]);
    } else {
        __syncthreads();
        __syncthreads();
    }
    __syncthreads();

    for (int h = tid; h < HDIM; h += 256) {
        const float* hsb = h_s + (size_t)b * HDIM + h;
        float acc = 0.f;
        #pragma unroll 4
        for (int t = 0; t < TPREM; ++t)
            acc = fmaf(alpha[t], hsb[(size_t)t * BATCH * HDIM], acc);
        a_out[(size_t)b * HDIM + h] = acc;
    }
}

__global__ void k_fc(const float* __restrict__ h_m,
                     const float* __restrict__ fc_w,
                     const float* __restrict__ fc_b,
                     float* __restrict__ out)
{
    const int b = threadIdx.x;
    float a0 = 0.f, a1 = 0.f, a2 = 0.f;
    for (int h = 0; h < HDIM; ++h) {
        float v = h_m[(size_t)b * HDIM + h];
        a0 = fmaf(v, fc_w[h], a0);
        a1 = fmaf(v, fc_w[HDIM + h], a1);
        a2 = fmaf(v, fc_w[2 * HDIM + h], a2);
    }
    out[b * 3 + 0] = a0 + fc_b[0];
    out[b * 3 + 1] = a1 + fc_b[1];
    out[b * 3 + 2] = a2 + fc_b[2];
}

// ===========================================================================
extern "C" void kernel_launch(void* const* d_in, const int* in_sizes, int n_in,
                              void* d_out, int out_size, void* d_ws, size_t ws_size,
                              hipStream_t stream) {
    (void)in_sizes; (void)n_in; (void)out_size;
    const int*   premise    = (const int*)d_in[0];
    const int*   hypothesis = (const int*)d_in[2];
    const float* w2v        = (const float*)d_in[4];
    const float* w_e        = (const float*)d_in[5];
    const float* W_s        = (const float*)d_in[6];
    const float* W_t        = (const float*)d_in[7];
    const float* W_m        = (const float*)d_in[8];
    const float* fc_w       = (const float*)d_in[9];
    const float* fc_b       = (const float*)d_in[10];
    const float* pWih       = (const float*)d_in[11];
    const float* pWhh       = (const float*)d_in[12];
    const float* pbih       = (const float*)d_in[13];
    const float* pbhh       = (const float*)d_in[14];
    const float* hWih       = (const float*)d_in[15];
    const float* hWhh       = (const float*)d_in[16];
    const float* hbih       = (const float*)d_in[17];
    const float* hbhh       = (const float*)d_in[18];
    const float* mWih       = (const float*)d_in[19];
    const float* mbih       = (const float*)d_in[21];
    const float* mbhh       = (const float*)d_in[22];

    const size_t BH = (size_t)BATCH * HDIM;
    const size_t F32_CNT = (size_t)TPREM * BH + 2 * (size_t)THYP * BH + 2 * BH;
    const size_t COOP_NEED = 4096 + F32_CNT * 4 + 2 * (size_t)TPREM * BH * 2; // ~119 MB

    bool coop_done = false;
    if (ws_size >= COOP_NEED) {
        int maxb = 0;
        hipError_t oe = hipOccupancyMaxActiveBlocksPerMultiprocessor(
            &maxb, match_kernel, NTHR, 0);
        if (oe == hipSuccess && maxb * 256 >= NBLK) {
            Params p;
            p.premise = premise; p.hypothesis = hypothesis;
            p.w2v = w2v; p.w_e = w_e;
            p.W_s = W_s; p.W_t = W_t; p.W_m = W_m;
            p.fc_w = fc_w; p.fc_b = fc_b;
            p.pWih = pWih; p.pWhh = pWhh; p.pbih = pbih; p.pbhh = pbhh;
            p.hWih = hWih; p.hWhh = hWhh; p.hbih = hbih; p.hbhh = hbhh;
            p.mWih = mWih; p.mbih = mbih; p.mbhh = mbhh;

            p.cnt = (unsigned*)d_ws;
            float* f = (float*)((char*)d_ws + 4096);
            p.h_s     = f; f += (size_t)TPREM * BH;
            p.h_t_all = f; f += (size_t)THYP * BH;
            p.wt_ht   = f; f += (size_t)THYP * BH;
            p.h_m     = f; f += BH;
            p.ab      = f; f += BH;
            p.wshsT   = (unsigned short*)f;
            p.hsT     = p.wshsT + (size_t)TPREM * BH;
            p.out = (float*)d_out;

            void* args[] = { (void*)&p };
            hipError_t le = hipLaunchCooperativeKernel(
                (void*)match_kernel, dim3(NBLK), dim3(NTHR), args, 0, stream);
            coop_done = (le == hipSuccess);
        }
    }
    if (coop_done) return;

    // ---- fallback: round-1 multi-kernel path ----
    float* ws    = (float*)d_ws;
    float* h_s   = ws;
    float* wshs  = h_s + (size_t)TPREM * BH;
    float* zeros = wshs + (size_t)TPREM * BH;
    float* c_p   = zeros + BH;
    float* c_h   = c_p + BH;
    float* c_m   = c_h + BH;
    float* ht0   = c_m + BH;
    float* ht1   = ht0 + BH;
    float* h_m   = ht1 + BH;
    float* qb    = h_m + BH;
    float* ab    = qb + BH;

    (void)hipMemsetAsync(zeros, 0, BH * sizeof(float), stream);
    (void)hipMemsetAsync(c_p,   0, BH * sizeof(float), stream);
    (void)hipMemsetAsync(c_h,   0, BH * sizeof(float), stream);
    (void)hipMemsetAsync(h_m,   0, BH * sizeof(float), stream);

    dim3 gGate(BATCH / 32, (HDIM + 15) / 16);

    for (int t = 0; t < TPREM; ++t) {
        const float* hp = t ? (h_s + (size_t)(t - 1) * BH) : zeros;
        k_lstm_gates<<<gGate, 256, 0, stream>>>(
            premise + (size_t)t * BATCH, w2v, nullptr, EDIM,
            hp, HDIM, pWih, EDIM, pWhh, HDIM,
            pbih, pbhh, c_p, c_p, h_s + (size_t)t * BH);
    }

    k_gemm_tn<64, 64, 4, 4, 16><<<dim3(TPREM * BATCH / 64, (HDIM + 63) / 64), 256, 0, stream>>>(
        h_s, HDIM, nullptr, 0, W_s, HDIM, nullptr, 0, wshs, TPREM * BATCH, HDIM);

    for (int k = 0; k < THYP; ++k) {
        const float* hp = k ? ((k & 1) ? ht0 : ht1) : zeros;
        float* hc = (k & 1) ? ht1 : ht0;
        k_lstm_gates<<<gGate, 256, 0, stream>>>(
            hypothesis + (size_t)k * BATCH, w2v, nullptr, EDIM,
            hp, HDIM, hWih, EDIM, hWhh, HDIM,
            hbih, hbhh, c_h, c_h, hc);
        k_gemm_tn<16, 64, 1, 4, 16><<<dim3(BATCH / 16, (HDIM + 63) / 64), 256, 0, stream>>>(
            hc, HDIM, h_m, HDIM, W_t, HDIM, W_m, HDIM, qb, BATCH, HDIM);
        k_attn<<<BATCH, 256, 0, stream>>>(wshs, h_s, qb, w_e, ab);
        k_lstm_gates<<<gGate, 256, 0, stream>>>(
            nullptr, nullptr, ab, HDIM,
            hc, HDIM, mWih, 2 * HDIM, mWih + HDIM, 2 * HDIM,
            mbih, mbhh, zeros, c_m, h_m);
    }

    k_fc<<<1, BATCH, 0, stream>>>(h_m, fc_w, fc_b, (float*)d_out);
}

// Round 8
// 14956.694 us; speedup vs baseline: 1.4966x; 1.4928x over previous
//
#include <hip/hip_runtime.h>
#include <hip/hip_bf16.h>
#include <cstddef>

// MatchLSTM round 8: three plain launches — k_zero, match_b (recurrences,
// R7-proven flag sync), match_d (match loop, 512 thr, vectorized/coalesced).
// Kernel split gives per-phase rocprof attribution.
// V=50000, E=300, H=300, C=3, TP=128, TH=64, B=256
#define HDIM 300
#define EDIM 300
#define BATCH 256
#define TPREM 128
#define THYP 64
#define NTHR 256
#define NTHR_D 512
#define NBLK 304
#define KTT 32

__device__ __forceinline__ float fast_sigm(float x) {
    return 1.f / (1.f + __expf(-x));
}
__device__ __forceinline__ float fast_tanh(float x) {
    float e = __expf(2.f * x);
    return 1.f - 2.f / (e + 1.f);
}
__device__ __forceinline__ unsigned short f2bf(float f) {
    __hip_bfloat16 h = __float2bfloat16(f);
    return *reinterpret_cast<unsigned short*>(&h);
}
__device__ __forceinline__ float bf2f(unsigned short u) {
    return __uint_as_float((unsigned)u << 16);
}
__device__ __forceinline__ float gload(const float* p) {
    return __hip_atomic_load(p, __ATOMIC_RELAXED, __HIP_MEMORY_SCOPE_AGENT);
}
__device__ __forceinline__ void gstore(float* p, float v) {
    __hip_atomic_store(p, v, __ATOMIC_RELAXED, __HIP_MEMORY_SCOPE_AGENT);
}

struct Params {
    const int* premise; const int* hypothesis;
    const float* w2v; const float* w_e;
    const float* W_s; const float* W_t; const float* W_m;
    const float* fc_w; const float* fc_b;
    const float* pWih; const float* pWhh; const float* pbih; const float* pbhh;
    const float* hWih; const float* hWhh; const float* hbih; const float* hbhh;
    const float* mWih; const float* mbih; const float* mbhh;
    float* h_s;      // [TP][B][H] fp32 (bypass h-exchange)
    float* h_t_all;  // [TH][B][H] fp32 (bypass write; cached read in D)
    float* wt_ht;    // [TH][B][H] fp32 (cached; visible to D via kernel boundary)
    float* h_m;      // [B][H] (bypass)
    float* ab;       // [B][H] (bypass)
    unsigned short* wshsT;  // [B][TP][H] bf16
    unsigned short* hsT;    // [B][TP][H] bf16
    unsigned* cnt;   // 32 counters, stride-32
    float* out;
};

// Relaxed flag sync; backoff capped at s_sleep(8) (~0.2us).
__device__ __forceinline__ void arrive(unsigned* slot) {
    __syncthreads();
    if (threadIdx.x == 0)
        __hip_atomic_fetch_add(slot, 1u, __ATOMIC_RELAXED, __HIP_MEMORY_SCOPE_AGENT);
}
__device__ __forceinline__ void wait_ge(unsigned* slot, unsigned target) {
    if (threadIdx.x == 0) {
        int sl = 0; long guard = 0;
        while (__hip_atomic_load(slot, __ATOMIC_RELAXED, __HIP_MEMORY_SCOPE_AGENT) < target) {
            if (sl < 4) __builtin_amdgcn_s_sleep(1);
            else        __builtin_amdgcn_s_sleep(8);
            ++sl;
            if (++guard > (1L << 18)) break;   // deadlock insurance
        }
    }
    __syncthreads();
}

// ===========================================================================
// k_zero: init h_m (bypass) + counters
// ===========================================================================
__global__ void k_zero(Params p) {
    int i = blockIdx.x * 256 + threadIdx.x;
    if (i < BATCH * HDIM) gstore(&p.h_m[i], 0.f);
    if (i < 1024)
        __hip_atomic_store(&p.cnt[i], 0u, __ATOMIC_RELAXED, __HIP_MEMORY_SCOPE_AGENT);
}

// ===========================================================================
// match_b: both recurrences (R7-proven structure), plain launch.
// blocks 0..151 premise (8 groups x 19), 152..303 hypothesis.
// ===========================================================================
struct SmemB { float hA[320][34]; float As[KTT][34]; float Bs[KTT][68]; };

__device__ void proj_from_hA(SmemB& sm, const float* Wp,
                             float* dstf, unsigned short* dstb, bool toBf16T,
                             int trow, int b0, int n0)
{
    const int tid = threadIdx.x;
    const int fb_c = tid >> 2, fb_k0 = (tid & 3) * 8;
    const int pb = tid & 15, hl = tid >> 4;
    const int wrow = n0 + fb_c;
    const bool wvalid = wrow < HDIM;
    float acc[2][4] = {};
    for (int kc = 0; kc < HDIM; kc += KTT) {
        #pragma unroll
        for (int u = 0; u < 8; ++u) {
            int kk = fb_k0 + u, k = kc + kk;
            sm.Bs[kk][fb_c] = (wvalid && k < HDIM)
                ? Wp[(size_t)wrow * HDIM + k] : 0.f;
        }
        __syncthreads();
        #pragma unroll
        for (int kk = 0; kk < KTT; ++kk) {
            float2 av = *(const float2*)&sm.hA[kc + kk][pb * 2];
            float4 wv = *(const float4*)&sm.Bs[kk][hl * 4];
            acc[0][0] = fmaf(av.x, wv.x, acc[0][0]);
            acc[0][1] = fmaf(av.x, wv.y, acc[0][1]);
            acc[0][2] = fmaf(av.x, wv.z, acc[0][2]);
            acc[0][3] = fmaf(av.x, wv.w, acc[0][3]);
            acc[1][0] = fmaf(av.y, wv.x, acc[1][0]);
            acc[1][1] = fmaf(av.y, wv.y, acc[1][1]);
            acc[1][2] = fmaf(av.y, wv.z, acc[1][2]);
            acc[1][3] = fmaf(av.y, wv.w, acc[1][3]);
        }
        __syncthreads();
    }
    const int col = n0 + hl * 4;
    #pragma unroll
    for (int u = 0; u < 2; ++u) {
        const int brow = b0 + pb * 2 + u;
        if (toBf16T) {
            if (col < HDIM) {
                ushort4 v4;
                v4.x = f2bf(acc[u][0]); v4.y = f2bf(acc[u][1]);
                v4.z = f2bf(acc[u][2]); v4.w = f2bf(acc[u][3]);
                *reinterpret_cast<ushort4*>(
                    &dstb[((size_t)brow * TPREM + trow) * HDIM + col]) = v4;
            }
        } else {
            size_t row = (size_t)trow * BATCH + brow;
            #pragma unroll
            for (int jc = 0; jc < 4; ++jc) {
                int c = col + jc;
                if (c < HDIM) dstf[row * HDIM + c] = acc[u][jc];
            }
        }
    }
}

__device__ __forceinline__ void stage_hA(SmemB& sm, const float* hrow_base, int b0) {
    const int tid = threadIdx.x;
    for (int idx = tid; idx < 32 * HDIM; idx += NTHR) {
        int r = idx / HDIM, k = idx - r * HDIM;
        sm.hA[k][r] = gload(&hrow_base[(size_t)(b0 + r) * HDIM + k]);
    }
    for (int idx = tid; idx < 20 * 34; idx += NTHR)
        sm.hA[300 + idx / 34][idx % 34] = 0.f;
    __syncthreads();
}

__global__ __launch_bounds__(NTHR, 2) void match_b(Params p) {
    __shared__ SmemB sm;
    const int blk = blockIdx.x;
    const int tid = threadIdx.x;
    const int pb = tid & 15, hl = tid >> 4;
    const size_t BH = (size_t)BATCH * HDIM;

    const bool isP = blk < 152;
    const int idx = isP ? blk : blk - 152;
    const int grp = idx / 19, nt = idx % 19;
    unsigned* gslot = &p.cnt[(isP ? grp : 8 + grp) * 32];
    const int b0 = grp * 32, hh0 = nt * 16;
    const int TSTEPS = isP ? TPREM : THYP;
    const int* toks = isP ? p.premise : p.hypothesis;
    const float* Wih = isP ? p.pWih : p.hWih;
    const float* Whh = isP ? p.pWhh : p.hWhh;
    const float* bihp = isP ? p.pbih : p.hbih;
    const float* bhhp = isP ? p.pbhh : p.hbhh;
    float* hseq = isP ? p.h_s : p.h_t_all;
    const float* Wproj = isP ? p.W_s : p.W_t;

    const int fa_b = tid >> 3;
    const int fa_k0 = (tid & 7) * 4;
    const int fb_c = tid >> 2;
    const int fb_k0 = (tid & 3) * 8;
    const int whh_l = hh0 + (fb_c >> 2);
    const int wrow = (fb_c & 3) * HDIM + whh_l;
    const bool wvalid = whh_l < HDIM;

    const int hh = hh0 + hl;
    float bi = 0.f, bf = 0.f, bg = 0.f, bo = 0.f;
    if (hh < HDIM) {
        bi = bihp[hh] + bhhp[hh];
        bf = bihp[HDIM + hh] + bhhp[HDIM + hh];
        bg = bihp[2 * HDIM + hh] + bhhp[2 * HDIM + hh];
        bo = bihp[3 * HDIM + hh] + bhhp[3 * HDIM + hh];
    }
    float creg[2] = {0.f, 0.f};

    for (int t = 0; t < TSTEPS; ++t) {
        if (t > 0) {
            wait_ge(gslot, 19u * (unsigned)t);
            stage_hA(sm, hseq + (size_t)(t - 1) * BH, b0);
        }
        float acc[2][4] = {};
        const float* xrow = p.w2v +
            (size_t)toks[(size_t)t * BATCH + b0 + fa_b] * EDIM;
        // x @ Wih^T
        for (int kc = 0; kc < EDIM; kc += KTT) {
            #pragma unroll
            for (int u = 0; u < 4; ++u) {
                int kk = fa_k0 + u, k = kc + kk;
                sm.As[kk][fa_b] = (k < EDIM) ? xrow[k] : 0.f;
            }
            #pragma unroll
            for (int u = 0; u < 8; ++u) {
                int kk = fb_k0 + u, k = kc + kk;
                sm.Bs[kk][fb_c] = (wvalid && k < EDIM)
                    ? Wih[(size_t)wrow * EDIM + k] : 0.f;
            }
            __syncthreads();
            #pragma unroll
            for (int kk = 0; kk < KTT; ++kk) {
                float2 av = *(const float2*)&sm.As[kk][pb * 2];
                float4 wv = *(const float4*)&sm.Bs[kk][hl * 4];
                acc[0][0] = fmaf(av.x, wv.x, acc[0][0]);
                acc[0][1] = fmaf(av.x, wv.y, acc[0][1]);
                acc[0][2] = fmaf(av.x, wv.z, acc[0][2]);
                acc[0][3] = fmaf(av.x, wv.w, acc[0][3]);
                acc[1][0] = fmaf(av.y, wv.x, acc[1][0]);
                acc[1][1] = fmaf(av.y, wv.y, acc[1][1]);
                acc[1][2] = fmaf(av.y, wv.z, acc[1][2]);
                acc[1][3] = fmaf(av.y, wv.w, acc[1][3]);
            }
            __syncthreads();
        }
        // h[t-1] @ Whh^T
        if (t > 0) {
            for (int kc = 0; kc < HDIM; kc += KTT) {
                #pragma unroll
                for (int u = 0; u < 8; ++u) {
                    int kk = fb_k0 + u, k = kc + kk;
                    sm.Bs[kk][fb_c] = (wvalid && k < HDIM)
                        ? Whh[(size_t)wrow * HDIM + k] : 0.f;
                }
                __syncthreads();
                #pragma unroll
                for (int kk = 0; kk < KTT; ++kk) {
                    float2 av = *(const float2*)&sm.hA[kc + kk][pb * 2];
                    float4 wv = *(const float4*)&sm.Bs[kk][hl * 4];
                    acc[0][0] = fmaf(av.x, wv.x, acc[0][0]);
                    acc[0][1] = fmaf(av.x, wv.y, acc[0][1]);
                    acc[0][2] = fmaf(av.x, wv.z, acc[0][2]);
                    acc[0][3] = fmaf(av.x, wv.w, acc[0][3]);
                    acc[1][0] = fmaf(av.y, wv.x, acc[1][0]);
                    acc[1][1] = fmaf(av.y, wv.y, acc[1][1]);
                    acc[1][2] = fmaf(av.y, wv.z, acc[1][2]);
                    acc[1][3] = fmaf(av.y, wv.w, acc[1][3]);
                }
                __syncthreads();
            }
        }
        if (hh < HDIM) {
            #pragma unroll
            for (int u = 0; u < 2; ++u) {
                int b = b0 + pb * 2 + u;
                float gi = fast_sigm(acc[u][0] + bi);
                float gf = fast_sigm(acc[u][1] + bf);
                float gg = fast_tanh(acc[u][2] + bg);
                float go = fast_sigm(acc[u][3] + bo);
                float c = gf * creg[u] + gi * gg;
                creg[u] = c;
                float hval = go * fast_tanh(c);
                gstore(&hseq[(size_t)t * BH + (size_t)b * HDIM + hh], hval);
                if (isP)
                    p.hsT[((size_t)b * TPREM + t) * HDIM + hh] = f2bf(hval);
            }
        }
        arrive(gslot);
        if (t > 0) {
            int jj = nt - (5 * (t - 1)) % 19; if (jj < 0) jj += 19;
            if (jj < 5)
                proj_from_hA(sm, Wproj, p.wt_ht, p.wshsT, isP, t - 1, b0, jj * 64);
        }
    }
    {
        int jj = nt - (5 * (TSTEPS - 1)) % 19; if (jj < 0) jj += 19;
        if (jj < 5) {
            wait_ge(gslot, 19u * (unsigned)TSTEPS);
            stage_hA(sm, hseq + (size_t)(TSTEPS - 1) * BH, b0);
            proj_from_hA(sm, Wproj, p.wt_ht, p.wshsT, isP, TSTEPS - 1, b0, jj * 64);
        }
    }
}

// ===========================================================================
// match_d: match loop, 256 blocks x 512 threads (block = batch element).
// ===========================================================================
__global__ __launch_bounds__(NTHR_D) void match_d(Params p) {
    __shared__ __align__(16) float q_s[304];
    __shared__ __align__(16) float we_s[304];
    __shared__ __align__(16) float hm_s[304];
    __shared__ float alpha[TPREM];
    __shared__ float red[32];
    __shared__ __align__(16) float pa[8][304];
    __shared__ __align__(16) float As[KTT][34];
    __shared__ __align__(16) float Bs[KTT][68];
    __shared__ float gbuf[32][68];

    const int b = blockIdx.x;
    const int tid = threadIdx.x;
    const int lane = tid & 63;
    const int wv = tid >> 6;            // 0..7
    const int bt = b >> 5, j = b & 31;
    const int b0 = bt * 32;
    const size_t BH = (size_t)BATCH * HDIM;
    unsigned* cA = &p.cnt[(16 + bt) * 32];
    unsigned* cC = &p.cnt[(24 + bt) * 32];
    const unsigned short* wsb = p.wshsT + (size_t)b * TPREM * HDIM;
    const unsigned short* hsb = p.hsT   + (size_t)b * TPREM * HDIM;

    for (int h = tid; h < HDIM; h += NTHR_D) we_s[h] = p.w_e[h];

    for (int k = 0; k < THYP; ++k) {
        wait_ge(cC, 19u * (unsigned)k);

        for (int h = tid; h < HDIM; h += NTHR_D)
            hm_s[h] = gload(&p.h_m[(size_t)b * HDIM + h]);
        __syncthreads();

        // q: wave-per-row, coalesced W_m row reads
        const float* wt = p.wt_ht + ((size_t)k * BATCH + b) * HDIM;
        for (int h = wv; h < HDIM; h += 8) {
            const float* wr = p.W_m + (size_t)h * HDIM;
            float a = 0.f;
            #pragma unroll
            for (int i = 0; i < 5; ++i) {
                int jj = lane + 64 * i;
                if (jj < HDIM) a = fmaf(wr[jj], hm_s[jj], a);
            }
            #pragma unroll
            for (int off = 32; off; off >>= 1) a += __shfl_xor(a, off, 64);
            if (lane == 0) q_s[h] = a + wt[h];
        }
        __syncthreads();

        // e-pass: ushort4 loads + float4 LDS
        for (int t = wv; t < TPREM; t += 8) {
            const unsigned short* row = wsb + (size_t)t * HDIM;
            ushort4 v4 = *reinterpret_cast<const ushort4*>(&row[4 * lane]);
            float4 qv = *reinterpret_cast<const float4*>(&q_s[4 * lane]);
            float4 wev = *reinterpret_cast<const float4*>(&we_s[4 * lane]);
            float pp;
            pp  = wev.x * fast_tanh(bf2f(v4.x) + qv.x);
            pp += wev.y * fast_tanh(bf2f(v4.y) + qv.y);
            pp += wev.z * fast_tanh(bf2f(v4.z) + qv.z);
            pp += wev.w * fast_tanh(bf2f(v4.w) + qv.w);
            if (lane < 44) {
                int h = 256 + lane;
                pp += we_s[h] * fast_tanh(bf2f(row[h]) + q_s[h]);
            }
            #pragma unroll
            for (int off = 32; off; off >>= 1) pp += __shfl_xor(pp, off, 64);
            if (lane == 0) alpha[t] = pp;
        }
        __syncthreads();

        // softmax over 128 (waves 0,1)
        if (wv < 2) {
            float ev = alpha[tid];
            float m = ev;
            #pragma unroll
            for (int off = 32; off; off >>= 1) m = fmaxf(m, __shfl_xor(m, off, 64));
            if (lane == 0) red[wv] = m;
            __syncthreads();
            float gm = fmaxf(red[0], red[1]);
            float e = __expf(ev - gm);
            alpha[tid] = e;
            float s = e;
            #pragma unroll
            for (int off = 32; off; off >>= 1) s += __shfl_xor(s, off, 64);
            if (lane == 0) red[2 + wv] = s;
            __syncthreads();
            alpha[tid] *= 1.f / (red[2] + red[3]);
        } else {
            __syncthreads();
            __syncthreads();
        }
        __syncthreads();

        // PV: ushort4 loads, per-wave accumulators, LDS cross-wave reduce
        {
            float a0 = 0.f, a1 = 0.f, a2 = 0.f, a3 = 0.f, at = 0.f;
            for (int t = wv; t < TPREM; t += 8) {
                float w = alpha[t];
                const unsigned short* row = hsb + (size_t)t * HDIM;
                ushort4 v4 = *reinterpret_cast<const ushort4*>(&row[4 * lane]);
                a0 = fmaf(w, bf2f(v4.x), a0);
                a1 = fmaf(w, bf2f(v4.y), a1);
                a2 = fmaf(w, bf2f(v4.z), a2);
                a3 = fmaf(w, bf2f(v4.w), a3);
                if (lane < 44) at = fmaf(w, bf2f(row[256 + lane]), at);
            }
            float4 av; av.x = a0; av.y = a1; av.z = a2; av.w = a3;
            *reinterpret_cast<float4*>(&pa[wv][4 * lane]) = av;
            if (lane < 44) pa[wv][256 + lane] = at;
            __syncthreads();
            for (int h = tid; h < HDIM; h += NTHR_D) {
                float s = 0.f;
                #pragma unroll
                for (int w8 = 0; w8 < 8; ++w8) s += pa[w8][h];
                gstore(&p.ab[(size_t)b * HDIM + h], s);
            }
        }
        arrive(cA);

        // match cell (j<19 blocks of each bt group): G = [ab|h_t] @ mWih^T
        if (j < 19) {
            wait_ge(cA, 32u * (unsigned)(k + 1));
            const float* htp = p.h_t_all + (size_t)k * BH;
            const int fa_b = tid >> 4;            // 0..31
            const int fa_k0 = (tid & 15) * 2;     // 2 consecutive k
            const int fb_c = tid >> 3;            // 0..63
            const int fb_k0 = (tid & 7) * 4;      // 4 consecutive k
            const int hh_c = j * 16 + (fb_c >> 2);
            const int wrow = (fb_c & 3) * HDIM + hh_c;
            const bool wvalid = hh_c < HDIM;
            const int pb2 = tid & 15, cl = tid >> 4;
            float acc[2][2] = {};
            for (int kc = 0; kc < 608; kc += KTT) {
                #pragma unroll
                for (int u = 0; u < 2; ++u) {
                    int kk = fa_k0 + u, kg = kc + kk;
                    float v = 0.f;
                    if (kg < HDIM)
                        v = gload(&p.ab[(size_t)(b0 + fa_b) * HDIM + kg]);
                    else if (kg < 600)
                        v = htp[(size_t)(b0 + fa_b) * HDIM + (kg - HDIM)];
                    As[kk][fa_b] = v;
                }
                #pragma unroll
                for (int u = 0; u < 4; ++u) {
                    int kk = fb_k0 + u, kg = kc + kk;
                    Bs[kk][fb_c] = (wvalid && kg < 600)
                        ? p.mWih[(size_t)wrow * 600 + kg] : 0.f;
                }
                __syncthreads();
                #pragma unroll
                for (int kk = 0; kk < KTT; ++kk) {
                    float2 av2 = *(const float2*)&As[kk][pb2 * 2];
                    float2 wv2 = *(const float2*)&Bs[kk][cl * 2];
                    acc[0][0] = fmaf(av2.x, wv2.x, acc[0][0]);
                    acc[0][1] = fmaf(av2.x, wv2.y, acc[0][1]);
                    acc[1][0] = fmaf(av2.y, wv2.x, acc[1][0]);
                    acc[1][1] = fmaf(av2.y, wv2.y, acc[1][1]);
                }
                __syncthreads();
            }
            #pragma unroll
            for (int u = 0; u < 2; ++u)
                #pragma unroll
                for (int v = 0; v < 2; ++v)
                    gbuf[pb2 * 2 + u][cl * 2 + v] = acc[u][v];
            __syncthreads();
            {
                const int bl = tid & 31, hl2 = tid >> 5;   // 0..15
                int hh = j * 16 + hl2;
                if (hh < HDIM) {
                    float g0 = gbuf[bl][hl2 * 4 + 0];
                    float g2 = gbuf[bl][hl2 * 4 + 2];
                    float g3 = gbuf[bl][hl2 * 4 + 3];
                    float bi0 = p.mbih[hh] + p.mbhh[hh];
                    float bi2 = p.mbih[2 * HDIM + hh] + p.mbhh[2 * HDIM + hh];
                    float bi3 = p.mbih[3 * HDIM + hh] + p.mbhh[3 * HDIM + hh];
                    float gi = fast_sigm(g0 + bi0);
                    float gg = fast_tanh(g2 + bi2);
                    float go = fast_sigm(g3 + bi3);
                    gstore(&p.h_m[(size_t)(b0 + bl) * HDIM + hh],
                           go * fast_tanh(gi * gg));
                }
            }
            arrive(cC);
        }
    }

    // FC
    wait_ge(cC, 19u * (unsigned)THYP);
    float p0 = 0.f, p1 = 0.f, p2 = 0.f;
    for (int h = tid; h < HDIM; h += NTHR_D) {
        float v = gload(&p.h_m[(size_t)b * HDIM + h]);
        p0 = fmaf(v, p.fc_w[h], p0);
        p1 = fmaf(v, p.fc_w[HDIM + h], p1);
        p2 = fmaf(v, p.fc_w[2 * HDIM + h], p2);
    }
    #pragma unroll
    for (int off = 32; off; off >>= 1) {
        p0 += __shfl_xor(p0, off, 64);
        p1 += __shfl_xor(p1, off, 64);
        p2 += __shfl_xor(p2, off, 64);
    }
    __syncthreads();
    if (lane == 0) {
        red[wv * 3 + 0] = p0;
        red[wv * 3 + 1] = p1;
        red[wv * 3 + 2] = p2;
    }
    __syncthreads();
    if (tid == 0) {
        float o0 = 0.f, o1 = 0.f, o2 = 0.f;
        #pragma unroll
        for (int w8 = 0; w8 < 8; ++w8) {
            o0 += red[w8 * 3 + 0];
            o1 += red[w8 * 3 + 1];
            o2 += red[w8 * 3 + 2];
        }
        p.out[b * 3 + 0] = o0 + p.fc_b[0];
        p.out[b * 3 + 1] = o1 + p.fc_b[1];
        p.out[b * 3 + 2] = o2 + p.fc_b[2];
    }
}

// ===========================================================================
// Fallback path: round-1 multi-kernel implementation (proven correct).
// ===========================================================================
__global__ void k_lstm_gates(
    const int* __restrict__ tok, const float* __restrict__ w2v,
    const float* __restrict__ A0, int K0,
    const float* __restrict__ A1, int K1,
    const float* __restrict__ W0, int ld0,
    const float* __restrict__ W1, int ld1,
    const float* __restrict__ bih, const float* __restrict__ bhh,
    const float* __restrict__ c_in, float* __restrict__ c_out,
    float* __restrict__ h_out)
{
    constexpr int KT = 32;
    __shared__ __align__(16) float As[KT][34];
    __shared__ __align__(16) float Bs[KT][68];

    const int tid = threadIdx.x;
    const int b0 = blockIdx.x * 32;
    const int hh0 = blockIdx.y * 16;
    const int K = K0 + K1;
    const int pb = tid & 15;
    const int hl = tid >> 4;
    const int fa_b = tid >> 3;
    const int fa_k0 = (tid & 7) * 4;
    const int fb_c = tid >> 2;
    const int fb_k0 = (tid & 3) * 8;
    const int fb_hh = hh0 + (fb_c >> 2);
    const int fb_g = fb_c & 3;
    const int fb_row = fb_g * HDIM + fb_hh;
    const bool fb_valid = fb_hh < HDIM;
    const int ga = b0 + fa_b;
    const int tok_b = tok ? tok[ga] : 0;

    float acc[2][4] = {{0.f,0.f,0.f,0.f},{0.f,0.f,0.f,0.f}};

    for (int k0 = 0; k0 < K; k0 += KT) {
        #pragma unroll
        for (int u = 0; u < 4; ++u) {
            int kk = fa_k0 + u;
            int k = k0 + kk;
            float v = 0.f;
            if (k < K0)      v = tok ? w2v[(size_t)tok_b * K0 + k]
                                     : A0[(size_t)ga * K0 + k];
            else if (k < K)  v = A1[(size_t)ga * K1 + (k - K0)];
            As[kk][fa_b] = v;
        }
        #pragma unroll
        for (int u = 0; u < 8; ++u) {
            int kk = fb_k0 + u;
            int k = k0 + kk;
            float v = 0.f;
            if (fb_valid) {
                if (k < K0)     v = W0[(size_t)fb_row * ld0 + k];
                else if (k < K) v = W1[(size_t)fb_row * ld1 + (k - K0)];
            }
            Bs[kk][fb_c] = v;
        }
        __syncthreads();
        #pragma unroll
        for (int kk = 0; kk < KT; ++kk) {
            float2 av = *(const float2*)&As[kk][pb * 2];
            float4 wv = *(const float4*)&Bs[kk][hl * 4];
            acc[0][0] = fmaf(av.x, wv.x, acc[0][0]);
            acc[0][1] = fmaf(av.x, wv.y, acc[0][1]);
            acc[0][2] = fmaf(av.x, wv.z, acc[0][2]);
            acc[0][3] = fmaf(av.x, wv.w, acc[0][3]);
            acc[1][0] = fmaf(av.y, wv.x, acc[1][0]);
            acc[1][1] = fmaf(av.y, wv.y, acc[1][1]);
            acc[1][2] = fmaf(av.y, wv.z, acc[1][2]);
            acc[1][3] = fmaf(av.y, wv.w, acc[1][3]);
        }
        __syncthreads();
    }

    const int hh = hh0 + hl;
    if (hh < HDIM) {
        float bi = bih[hh] + bhh[hh];
        float bf = bih[HDIM + hh] + bhh[HDIM + hh];
        float bg = bih[2 * HDIM + hh] + bhh[2 * HDIM + hh];
        float bo = bih[3 * HDIM + hh] + bhh[3 * HDIM + hh];
        #pragma unroll
        for (int u = 0; u < 2; ++u) {
            int b = b0 + pb * 2 + u;
            float gi = fast_sigm(acc[u][0] + bi);
            float gf = fast_sigm(acc[u][1] + bf);
            float gg = fast_tanh(acc[u][2] + bg);
            float go = fast_sigm(acc[u][3] + bo);
            float c = gf * c_in[(size_t)b * HDIM + hh] + gi * gg;
            c_out[(size_t)b * HDIM + hh] = c;
            h_out[(size_t)b * HDIM + hh] = go * fast_tanh(c);
        }
    }
}

template<int BM, int BN, int TM, int TN, int KT>
__global__ void k_gemm_tn(
    const float* __restrict__ A0, int K0,
    const float* __restrict__ A1, int K1,
    const float* __restrict__ B0, int ldb0,
    const float* __restrict__ B1, int ldb1,
    float* __restrict__ C, int M, int N)
{
    __shared__ __align__(16) float As[KT][BM + 4];
    __shared__ __align__(16) float Bs[KT][BN + 4];
    const int tid = threadIdx.x;
    const int m0 = blockIdx.x * BM;
    const int n0 = blockIdx.y * BN;
    const int K = K0 + K1;
    constexpr int TPM = BM / TM;
    const int tm = tid % TPM;
    const int tn = tid / TPM;

    float acc[TM][TN];
    #pragma unroll
    for (int i = 0; i < TM; ++i)
        #pragma unroll
        for (int j = 0; j < TN; ++j) acc[i][j] = 0.f;

    for (int k0 = 0; k0 < K; k0 += KT) {
        for (int i = tid; i < KT * BM; i += 256) {
            int kk = i % KT, ml = i / KT;
            int m = m0 + ml, k = k0 + kk;
            float v = 0.f;
            if (m < M) {
                if (k < K0)     v = A0[(size_t)m * K0 + k];
                else if (k < K) v = A1[(size_t)m * K1 + (k - K0)];
            }
            As[kk][ml] = v;
        }
        for (int i = tid; i < KT * BN; i += 256) {
            int kk = i % KT, nl = i / KT;
            int n = n0 + nl, k = k0 + kk;
            float v = 0.f;
            if (n < N) {
                if (k < K0)     v = B0[(size_t)n * ldb0 + k];
                else if (k < K) v = B1[(size_t)n * ldb1 + (k - K0)];
            }
            Bs[kk][nl] = v;
        }
        __syncthreads();
        #pragma unroll
        for (int kk = 0; kk < KT; ++kk) {
            float a[TM], w[TN];
            #pragma unroll
            for (int i = 0; i < TM; ++i) a[i] = As[kk][tm * TM + i];
            #pragma unroll
            for (int j = 0; j < TN; ++j) w[j] = Bs[kk][tn * TN + j];
            #pragma unroll
            for (int i = 0; i < TM; ++i)
                #pragma unroll
                for (int j = 0; j < TN; ++j)
                    acc[i][j] = fmaf(a[i], w[j], acc[i][j]);
        }
        __syncthreads();
    }
    #pragma unroll
    for (int i = 0; i < TM; ++i) {
        int m = m0 + tm * TM + i;
        if (m >= M) continue;
        #pragma unroll
        for (int j = 0; j < TN; ++j) {
            int n = n0 + tn * TN + j;
            if (n < N) C[(size_t)m * N + n] = acc[i][j];
        }
    }
}

__global__ void k_attn(const float* __restrict__ ws_hs,
                       const float* __restrict__ h_s,
                       const float* __restrict__ q,
                       const float* __restrict__ w_e,
                       float* __restrict__ a_out)
{
    const int b = blockIdx.x;
    const int tid = threadIdx.x;
    const int lane = tid & 63;
    const int wv = tid >> 6;

    __shared__ float q_s[HDIM];
    __shared__ float we_s[HDIM];
    __shared__ float alpha[TPREM];
    __shared__ float red[4];

    for (int h = tid; h < HDIM; h += 256) {
        q_s[h] = q[(size_t)b * HDIM + h];
        we_s[h] = w_e[h];
    }
    __syncthreads();

    for (int t = wv; t < TPREM; t += 4) {
        const float* row = ws_hs + ((size_t)t * BATCH + b) * HDIM;
        float p = 0.f;
        for (int h = lane; h < HDIM; h += 64)
            p += we_s[h] * fast_tanh(row[h] + q_s[h]);
        #pragma unroll
        for (int off = 32; off; off >>= 1) p += __shfl_xor(p, off, 64);
        if (lane == 0) alpha[t] = p;
    }
    __syncthreads();

    if (wv < 2) {
        float ev = alpha[tid];
        float m = ev;
        #pragma unroll
        for (int off = 32; off; off >>= 1) m = fmaxf(m, __shfl_xor(m, off, 64));
        if (lane == 0) red[wv] = m;
        __syncthreads();
        float gm = fmaxf(red[0], red[1]);
        float e = __expf(ev - gm);
        alpha[tid] = e;
        float s = e;
        #pragma unroll
        for (int off = 32; off; off >>= 1) s += __shfl_xor(s, off, 64);
        if (lane == 0) red[2 + wv] = s;
        __syncthreads();
        alpha[tid] *= 1.f / (red[2] + red[3]);
    } else {
        __syncthreads();
        __syncthreads();
    }
    __syncthreads();

    for (int h = tid; h < HDIM; h += 256) {
        const float* hsb = h_s + (size_t)b * HDIM + h;
        float acc = 0.f;
        #pragma unroll 4
        for (int t = 0; t < TPREM; ++t)
            acc = fmaf(alpha[t], hsb[(size_t)t * BATCH * HDIM], acc);
        a_out[(size_t)b * HDIM + h] = acc;
    }
}

__global__ void k_fc(const float* __restrict__ h_m,
                     const float* __restrict__ fc_w,
                     const float* __restrict__ fc_b,
                     float* __restrict__ out)
{
    const int b = threadIdx.x;
    float a0 = 0.f, a1 = 0.f, a2 = 0.f;
    for (int h = 0; h < HDIM; ++h) {
        float v = h_m[(size_t)b * HDIM + h];
        a0 = fmaf(v, fc_w[h], a0);
        a1 = fmaf(v, fc_w[HDIM + h], a1);
        a2 = fmaf(v, fc_w[2 * HDIM + h], a2);
    }
    out[b * 3 + 0] = a0 + fc_b[0];
    out[b * 3 + 1] = a1 + fc_b[1];
    out[b * 3 + 2] = a2 + fc_b[2];
}

// ===========================================================================
extern "C" void kernel_launch(void* const* d_in, const int* in_sizes, int n_in,
                              void* d_out, int out_size, void* d_ws, size_t ws_size,
                              hipStream_t stream) {
    (void)in_sizes; (void)n_in; (void)out_size;
    const int*   premise    = (const int*)d_in[0];
    const int*   hypothesis = (const int*)d_in[2];
    const float* w2v        = (const float*)d_in[4];
    const float* w_e        = (const float*)d_in[5];
    const float* W_s        = (const float*)d_in[6];
    const float* W_t        = (const float*)d_in[7];
    const float* W_m        = (const float*)d_in[8];
    const float* fc_w       = (const float*)d_in[9];
    const float* fc_b       = (const float*)d_in[10];
    const float* pWih       = (const float*)d_in[11];
    const float* pWhh       = (const float*)d_in[12];
    const float* pbih       = (const float*)d_in[13];
    const float* pbhh       = (const float*)d_in[14];
    const float* hWih       = (const float*)d_in[15];
    const float* hWhh       = (const float*)d_in[16];
    const float* hbih       = (const float*)d_in[17];
    const float* hbhh       = (const float*)d_in[18];
    const float* mWih       = (const float*)d_in[19];
    const float* mbih       = (const float*)d_in[21];
    const float* mbhh       = (const float*)d_in[22];

    const size_t BH = (size_t)BATCH * HDIM;
    const size_t F32_CNT = (size_t)TPREM * BH + 2 * (size_t)THYP * BH + 2 * BH;
    const size_t NEED = 4096 + F32_CNT * 4 + 2 * (size_t)TPREM * BH * 2;  // ~119 MB

    if (ws_size >= NEED) {
        Params p;
        p.premise = premise; p.hypothesis = hypothesis;
        p.w2v = w2v; p.w_e = w_e;
        p.W_s = W_s; p.W_t = W_t; p.W_m = W_m;
        p.fc_w = fc_w; p.fc_b = fc_b;
        p.pWih = pWih; p.pWhh = pWhh; p.pbih = pbih; p.pbhh = pbhh;
        p.hWih = hWih; p.hWhh = hWhh; p.hbih = hbih; p.hbhh = hbhh;
        p.mWih = mWih; p.mbih = mbih; p.mbhh = mbhh;

        p.cnt = (unsigned*)d_ws;
        float* f = (float*)((char*)d_ws + 4096);
        p.h_s     = f; f += (size_t)TPREM * BH;
        p.h_t_all = f; f += (size_t)THYP * BH;
        p.wt_ht   = f; f += (size_t)THYP * BH;
        p.h_m     = f; f += BH;
        p.ab      = f; f += BH;
        p.wshsT   = (unsigned short*)f;
        p.hsT     = p.wshsT + (size_t)TPREM * BH;
        p.out = (float*)d_out;

        k_zero<<<(int)((BATCH * HDIM + 255) / 256), 256, 0, stream>>>(p);
        match_b<<<NBLK, NTHR, 0, stream>>>(p);
        match_d<<<BATCH, NTHR_D, 0, stream>>>(p);
        return;
    }

    // ---- fallback: round-1 multi-kernel path ----
    float* ws    = (float*)d_ws;
    float* h_s   = ws;
    float* wshs  = h_s + (size_t)TPREM * BH;
    float* zeros = wshs + (size_t)TPREM * BH;
    float* c_p   = zeros + BH;
    float* c_h   = c_p + BH;
    float* c_m   = c_h + BH;
    float* ht0   = c_m + BH;
    float* ht1   = ht0 + BH;
    float* h_m   = ht1 + BH;
    float* qb    = h_m + BH;
    float* ab    = qb + BH;

    (void)hipMemsetAsync(zeros, 0, BH * sizeof(float), stream);
    (void)hipMemsetAsync(c_p,   0, BH * sizeof(float), stream);
    (void)hipMemsetAsync(c_h,   0, BH * sizeof(float), stream);
    (void)hipMemsetAsync(h_m,   0, BH * sizeof(float), stream);

    dim3 gGate(BATCH / 32, (HDIM + 15) / 16);

    for (int t = 0; t < TPREM; ++t) {
        const float* hp = t ? (h_s + (size_t)(t - 1) * BH) : zeros;
        k_lstm_gates<<<gGate, 256, 0, stream>>>(
            premise + (size_t)t * BATCH, w2v, nullptr, EDIM,
            hp, HDIM, pWih, EDIM, pWhh, HDIM,
            pbih, pbhh, c_p, c_p, h_s + (size_t)t * BH);
    }

    k_gemm_tn<64, 64, 4, 4, 16><<<dim3(TPREM * BATCH / 64, (HDIM + 63) / 64), 256, 0, stream>>>(
        h_s, HDIM, nullptr, 0, W_s, HDIM, nullptr, 0, wshs, TPREM * BATCH, HDIM);

    for (int k = 0; k < THYP; ++k) {
        const float* hp = k ? ((k & 1) ? ht0 : ht1) : zeros;
        float* hc = (k & 1) ? ht1 : ht0;
        k_lstm_gates<<<gGate, 256, 0, stream>>>(
            hypothesis + (size_t)k * BATCH, w2v, nullptr, EDIM,
            hp, HDIM, hWih, EDIM, hWhh, HDIM,
            hbih, hbhh, c_h, c_h, hc);
        k_gemm_tn<16, 64, 1, 4, 16><<<dim3(BATCH / 16, (HDIM + 63) / 64), 256, 0, stream>>>(
            hc, HDIM, h_m, HDIM, W_t, HDIM, W_m, HDIM, qb, BATCH, HDIM);
        k_attn<<<BATCH, 256, 0, stream>>>(wshs, h_s, qb, w_e, ab);
        k_lstm_gates<<<gGate, 256, 0, stream>>>(
            nullptr, nullptr, ab, HDIM,
            hc, HDIM, mWih, 2 * HDIM, mWih + HDIM, 2 * HDIM,
            mbih, mbhh, zeros, c_m, h_m);
    }

    k_fc<<<1, BATCH, 0, stream>>>(h_m, fc_w, fc_b, (float*)d_out);
}

// Round 9
// 13674.956 us; speedup vs baseline: 1.6369x; 1.0937x over previous
//
#include <hip/hip_runtime.h>
#include <hip/hip_bf16.h>
#include <cstddef>

// MatchLSTM round 9: bf16 weights (L2-resident recurrence), projections moved
// to bulk k_proj, match_d cell GEMM LDS-staged (batched bypass loads).
// Launches: k_init, match_b, k_proj, match_d.
// V=50000, E=300, H=300, C=3, TP=128, TH=64, B=256
#define HDIM 300
#define EDIM 300
#define BATCH 256
#define TPREM 128
#define THYP 64
#define NTHR 256
#define NTHR_D 512
#define NBLK 304
#define KTT 32

__device__ __forceinline__ float fast_sigm(float x) {
    return 1.f / (1.f + __expf(-x));
}
__device__ __forceinline__ float fast_tanh(float x) {
    float e = __expf(2.f * x);
    return 1.f - 2.f / (e + 1.f);
}
__device__ __forceinline__ unsigned short f2bf(float f) {
    __hip_bfloat16 h = __float2bfloat16(f);
    return *reinterpret_cast<unsigned short*>(&h);
}
__device__ __forceinline__ float bf2f(unsigned short u) {
    return __uint_as_float((unsigned)u << 16);
}
__device__ __forceinline__ float gload(const float* p) {
    return __hip_atomic_load(p, __ATOMIC_RELAXED, __HIP_MEMORY_SCOPE_AGENT);
}
__device__ __forceinline__ void gstore(float* p, float v) {
    __hip_atomic_store(p, v, __ATOMIC_RELAXED, __HIP_MEMORY_SCOPE_AGENT);
}

struct Params {
    const int* premise; const int* hypothesis;
    const float* w2v; const float* w_e;
    const float* W_s; const float* W_t; const float* W_m;
    const float* fc_w; const float* fc_b;
    const float* pWih; const float* pWhh; const float* pbih; const float* pbhh;
    const float* hWih; const float* hWhh; const float* hbih; const float* hbhh;
    const float* mWih; const float* mbih; const float* mbhh;
    float* h_s;      // [TP][B][H] fp32 (bypass h-exchange)
    float* h_t_all;  // [TH][B][H] fp32 (bypass write; cached read later)
    float* h_m;      // [B][H] (bypass)
    float* ab;       // [B][H] (bypass)
    unsigned short* wshsT;  // [B][TP][H] bf16 (k_proj)
    unsigned short* hsT;    // [B][TP][H] bf16 (inline in match_b)
    unsigned short* wthtB;  // [TH][B][H] bf16 (k_proj)
    unsigned short* wbuf;   // bf16 weights: pWih,pWhh,hWih,hWhh,mWih
    unsigned* cnt;
    float* out;
};
#define WB_PWIH 0
#define WB_PWHH 360000
#define WB_HWIH 720000
#define WB_HWHH 1080000
#define WB_MWIH 1440000
#define WB_TOT  2160000

// Relaxed flag sync (R6/R8-proven).
__device__ __forceinline__ void arrive(unsigned* slot) {
    __syncthreads();
    if (threadIdx.x == 0)
        __hip_atomic_fetch_add(slot, 1u, __ATOMIC_RELAXED, __HIP_MEMORY_SCOPE_AGENT);
}
__device__ __forceinline__ void wait_ge(unsigned* slot, unsigned target) {
    if (threadIdx.x == 0) {
        int sl = 0; long guard = 0;
        while (__hip_atomic_load(slot, __ATOMIC_RELAXED, __HIP_MEMORY_SCOPE_AGENT) < target) {
            if (sl < 4) __builtin_amdgcn_s_sleep(1);
            else        __builtin_amdgcn_s_sleep(8);
            ++sl;
            if (++guard > (1L << 18)) break;
        }
    }
    __syncthreads();
}

// ===========================================================================
// k_init: zero h_m/cnt, convert the 5 gate-weight matrices to bf16.
// ===========================================================================
__global__ void k_init(Params p) {
    const int stride = gridDim.x * 256;
    int i0 = blockIdx.x * 256 + threadIdx.x;
    for (int i = i0; i < WB_TOT; i += stride) {
        float v;
        if (i < WB_PWHH)      v = p.pWih[i];
        else if (i < WB_HWIH) v = p.pWhh[i - WB_PWHH];
        else if (i < WB_HWHH) v = p.hWih[i - WB_HWIH];
        else if (i < WB_MWIH) v = p.hWhh[i - WB_HWHH];
        else                  v = p.mWih[i - WB_MWIH];
        p.wbuf[i] = f2bf(v);
    }
    for (int i = i0; i < BATCH * HDIM; i += stride) gstore(&p.h_m[i], 0.f);
    for (int i = i0; i < 1024; i += stride)
        __hip_atomic_store(&p.cnt[i], 0u, __ATOMIC_RELAXED, __HIP_MEMORY_SCOPE_AGENT);
}

// ===========================================================================
// match_b: recurrences only. 8 groups x 19 blocks each for premise and hyp.
// bf16 weights (L2-resident slices), x gathered fp32 from w2v.
// ===========================================================================
__global__ __launch_bounds__(NTHR, 2) void match_b(Params p) {
    __shared__ __align__(16) float hA[320][34];
    __shared__ __align__(16) float As[KTT][34];
    __shared__ __align__(16) float Bs[KTT][68];

    const int blk = blockIdx.x;
    const int tid = threadIdx.x;
    const int pb = tid & 15, hl = tid >> 4;
    const size_t BH = (size_t)BATCH * HDIM;

    const bool isP = blk < 152;
    const int idx = isP ? blk : blk - 152;
    const int grp = idx / 19, nt = idx % 19;
    unsigned* gslot = &p.cnt[(isP ? grp : 8 + grp) * 32];
    const int b0 = grp * 32, hh0 = nt * 16;
    const int TSTEPS = isP ? TPREM : THYP;
    const int* toks = isP ? p.premise : p.hypothesis;
    const unsigned short* WihB = p.wbuf + (isP ? WB_PWIH : WB_HWIH);
    const unsigned short* WhhB = p.wbuf + (isP ? WB_PWHH : WB_HWHH);
    const float* bihp = isP ? p.pbih : p.hbih;
    const float* bhhp = isP ? p.pbhh : p.hbhh;
    float* hseq = isP ? p.h_s : p.h_t_all;

    const int fa_b = tid >> 3;
    const int fa_k0 = (tid & 7) * 4;
    const int fb_c = tid >> 2;
    const int fb_k0 = (tid & 3) * 8;
    const int whh_l = hh0 + (fb_c >> 2);
    const int wrow = (fb_c & 3) * HDIM + whh_l;
    const bool wvalid = whh_l < HDIM;

    const int hh = hh0 + hl;
    float bi = 0.f, bf = 0.f, bg = 0.f, bo = 0.f;
    if (hh < HDIM) {
        bi = bihp[hh] + bhhp[hh];
        bf = bihp[HDIM + hh] + bhhp[HDIM + hh];
        bg = bihp[2 * HDIM + hh] + bhhp[2 * HDIM + hh];
        bo = bihp[3 * HDIM + hh] + bhhp[3 * HDIM + hh];
    }
    float creg[2] = {0.f, 0.f};

    for (int t = 0; t < TSTEPS; ++t) {
        if (t > 0) {
            wait_ge(gslot, 19u * (unsigned)t);
            // stage h[t-1] (bypass, batched)
            const float* hb = hseq + (size_t)(t - 1) * BH;
            for (int i2 = tid; i2 < 32 * HDIM; i2 += NTHR) {
                int r = i2 / HDIM, k = i2 - r * HDIM;
                hA[k][r] = gload(&hb[(size_t)(b0 + r) * HDIM + k]);
            }
            for (int i2 = tid; i2 < 20 * 34; i2 += NTHR)
                hA[300 + i2 / 34][i2 % 34] = 0.f;
            __syncthreads();
        }
        float acc[2][4] = {};
        const float* xrow = p.w2v +
            (size_t)toks[(size_t)t * BATCH + b0 + fa_b] * EDIM;
        // x @ Wih^T (bf16 weights)
        for (int kc = 0; kc < EDIM; kc += KTT) {
            #pragma unroll
            for (int u = 0; u < 4; ++u) {
                int kk = fa_k0 + u, k = kc + kk;
                As[kk][fa_b] = (k < EDIM) ? xrow[k] : 0.f;
            }
            #pragma unroll
            for (int u = 0; u < 8; ++u) {
                int kk = fb_k0 + u, k = kc + kk;
                Bs[kk][fb_c] = (wvalid && k < EDIM)
                    ? bf2f(WihB[(size_t)wrow * EDIM + k]) : 0.f;
            }
            __syncthreads();
            #pragma unroll
            for (int kk = 0; kk < KTT; ++kk) {
                float2 av = *(const float2*)&As[kk][pb * 2];
                float4 wv = *(const float4*)&Bs[kk][hl * 4];
                acc[0][0] = fmaf(av.x, wv.x, acc[0][0]);
                acc[0][1] = fmaf(av.x, wv.y, acc[0][1]);
                acc[0][2] = fmaf(av.x, wv.z, acc[0][2]);
                acc[0][3] = fmaf(av.x, wv.w, acc[0][3]);
                acc[1][0] = fmaf(av.y, wv.x, acc[1][0]);
                acc[1][1] = fmaf(av.y, wv.y, acc[1][1]);
                acc[1][2] = fmaf(av.y, wv.z, acc[1][2]);
                acc[1][3] = fmaf(av.y, wv.w, acc[1][3]);
            }
            __syncthreads();
        }
        // h[t-1] @ Whh^T (bf16 weights)
        if (t > 0) {
            for (int kc = 0; kc < HDIM; kc += KTT) {
                #pragma unroll
                for (int u = 0; u < 8; ++u) {
                    int kk = fb_k0 + u, k = kc + kk;
                    Bs[kk][fb_c] = (wvalid && k < HDIM)
                        ? bf2f(WhhB[(size_t)wrow * HDIM + k]) : 0.f;
                }
                __syncthreads();
                #pragma unroll
                for (int kk = 0; kk < KTT; ++kk) {
                    float2 av = *(const float2*)&hA[kc + kk][pb * 2];
                    float4 wv = *(const float4*)&Bs[kk][hl * 4];
                    acc[0][0] = fmaf(av.x, wv.x, acc[0][0]);
                    acc[0][1] = fmaf(av.x, wv.y, acc[0][1]);
                    acc[0][2] = fmaf(av.x, wv.z, acc[0][2]);
                    acc[0][3] = fmaf(av.x, wv.w, acc[0][3]);
                    acc[1][0] = fmaf(av.y, wv.x, acc[1][0]);
                    acc[1][1] = fmaf(av.y, wv.y, acc[1][1]);
                    acc[1][2] = fmaf(av.y, wv.z, acc[1][2]);
                    acc[1][3] = fmaf(av.y, wv.w, acc[1][3]);
                }
                __syncthreads();
            }
        }
        if (hh < HDIM) {
            #pragma unroll
            for (int u = 0; u < 2; ++u) {
                int b = b0 + pb * 2 + u;
                float gi = fast_sigm(acc[u][0] + bi);
                float gf = fast_sigm(acc[u][1] + bf);
                float gg = fast_tanh(acc[u][2] + bg);
                float go = fast_sigm(acc[u][3] + bo);
                float c = gf * creg[u] + gi * gg;
                creg[u] = c;
                float hval = go * fast_tanh(c);
                gstore(&hseq[(size_t)t * BH + (size_t)b * HDIM + hh], hval);
                if (isP)
                    p.hsT[((size_t)b * TPREM + t) * HDIM + hh] = f2bf(hval);
            }
        }
        arrive(gslot);
    }
}

// ===========================================================================
// k_proj: bulk projections after the recurrence.
// Premise jobs 0..1023:  wshsT[b][t][:] = h_s row @ W_s^T (bf16 transposed)
// Hyp jobs 1024..1535:   wthtB[t][b][:] = h_t row @ W_t^T (bf16)
// ===========================================================================
__global__ __launch_bounds__(NTHR, 2) void k_proj(Params p) {
    __shared__ __align__(16) float hA[320][34];
    __shared__ __align__(16) float Bs[KTT][68];

    const int jb = blockIdx.x;
    const int tid = threadIdx.x;
    const int pb = tid & 15, hl = tid >> 4;
    const bool isP = jb < 1024;
    const int rt = isP ? jb : jb - 1024;
    const float* src = isP ? p.h_s : p.h_t_all;
    const float* Wp = isP ? p.W_s : p.W_t;
    const int fb_c = tid >> 2, fb_k0 = (tid & 3) * 8;

    // stage 32 rows (cached reads; kernel boundary fenced match_b's stores)
    for (int i2 = tid; i2 < 32 * HDIM; i2 += NTHR) {
        int r = i2 / HDIM, k = i2 - r * HDIM;
        hA[k][r] = src[(size_t)(rt * 32 + r) * HDIM + k];
    }
    for (int i2 = tid; i2 < 20 * 34; i2 += NTHR)
        hA[300 + i2 / 34][i2 % 34] = 0.f;
    __syncthreads();

    for (int n0 = 0; n0 < HDIM; n0 += 64) {
        const int wrow = n0 + fb_c;
        const bool wvalid = wrow < HDIM;
        float acc[2][4] = {};
        for (int kc = 0; kc < HDIM; kc += KTT) {
            #pragma unroll
            for (int u = 0; u < 8; ++u) {
                int kk = fb_k0 + u, k = kc + kk;
                Bs[kk][fb_c] = (wvalid && k < HDIM)
                    ? Wp[(size_t)wrow * HDIM + k] : 0.f;
            }
            __syncthreads();
            #pragma unroll
            for (int kk = 0; kk < KTT; ++kk) {
                float2 av = *(const float2*)&hA[kc + kk][pb * 2];
                float4 wv = *(const float4*)&Bs[kk][hl * 4];
                acc[0][0] = fmaf(av.x, wv.x, acc[0][0]);
                acc[0][1] = fmaf(av.x, wv.y, acc[0][1]);
                acc[0][2] = fmaf(av.x, wv.z, acc[0][2]);
                acc[0][3] = fmaf(av.x, wv.w, acc[0][3]);
                acc[1][0] = fmaf(av.y, wv.x, acc[1][0]);
                acc[1][1] = fmaf(av.y, wv.y, acc[1][1]);
                acc[1][2] = fmaf(av.y, wv.z, acc[1][2]);
                acc[1][3] = fmaf(av.y, wv.w, acc[1][3]);
            }
            __syncthreads();
        }
        const int col = n0 + hl * 4;
        if (col < HDIM) {
            #pragma unroll
            for (int u = 0; u < 2; ++u) {
                int rr = rt * 32 + pb * 2 + u;
                ushort4 v4;
                v4.x = f2bf(acc[u][0]); v4.y = f2bf(acc[u][1]);
                v4.z = f2bf(acc[u][2]); v4.w = f2bf(acc[u][3]);
                if (isP) {
                    int t = rr >> 8, b = rr & 255;
                    *reinterpret_cast<ushort4*>(
                        &p.wshsT[((size_t)b * TPREM + t) * HDIM + col]) = v4;
                } else {
                    *reinterpret_cast<ushort4*>(
                        &p.wthtB[(size_t)rr * HDIM + col]) = v4;
                }
            }
        }
        __syncthreads();
    }
}

// ===========================================================================
// match_d: match loop, 256 blocks x 512 threads; cell GEMM LDS-staged.
// ===========================================================================
__global__ __launch_bounds__(NTHR_D) void match_d(Params p) {
    __shared__ __align__(16) float q_s[304];
    __shared__ __align__(16) float we_s[304];
    __shared__ __align__(16) float hm_s[304];
    __shared__ float alpha[TPREM];
    __shared__ float red[32];
    __shared__ union {
        float pa[8][304];
        struct { float ab_s[32][304]; float ht_s[32][304]; } c;
    } U;
    __shared__ __align__(16) float As[KTT][34];
    __shared__ __align__(16) float Bs[KTT][68];
    __shared__ float gbuf[32][68];

    const int b = blockIdx.x;
    const int tid = threadIdx.x;
    const int lane = tid & 63;
    const int wv = tid >> 6;            // 0..7
    const int bt = b >> 5, j = b & 31;
    const int b0 = bt * 32;
    const size_t BH = (size_t)BATCH * HDIM;
    unsigned* cA = &p.cnt[(16 + bt) * 32];
    unsigned* cC = &p.cnt[(24 + bt) * 32];
    const unsigned short* wsb = p.wshsT + (size_t)b * TPREM * HDIM;
    const unsigned short* hsb = p.hsT   + (size_t)b * TPREM * HDIM;
    const unsigned short* mWihB = p.wbuf + WB_MWIH;

    for (int h = tid; h < HDIM; h += NTHR_D) we_s[h] = p.w_e[h];

    for (int k = 0; k < THYP; ++k) {
        wait_ge(cC, 19u * (unsigned)k);

        for (int h = tid; h < HDIM; h += NTHR_D)
            hm_s[h] = gload(&p.h_m[(size_t)b * HDIM + h]);
        __syncthreads();

        // q: wave-per-row, coalesced W_m rows
        const unsigned short* wt = p.wthtB + ((size_t)k * BATCH + b) * HDIM;
        for (int h = wv; h < HDIM; h += 8) {
            const float* wr = p.W_m + (size_t)h * HDIM;
            float a = 0.f;
            #pragma unroll
            for (int i = 0; i < 5; ++i) {
                int jj = lane + 64 * i;
                if (jj < HDIM) a = fmaf(wr[jj], hm_s[jj], a);
            }
            #pragma unroll
            for (int off = 32; off; off >>= 1) a += __shfl_xor(a, off, 64);
            if (lane == 0) q_s[h] = a + bf2f(wt[h]);
        }
        __syncthreads();

        // e-pass
        for (int t = wv; t < TPREM; t += 8) {
            const unsigned short* row = wsb + (size_t)t * HDIM;
            ushort4 v4 = *reinterpret_cast<const ushort4*>(&row[4 * lane]);
            float4 qv = *reinterpret_cast<const float4*>(&q_s[4 * lane]);
            float4 wev = *reinterpret_cast<const float4*>(&we_s[4 * lane]);
            float pp;
            pp  = wev.x * fast_tanh(bf2f(v4.x) + qv.x);
            pp += wev.y * fast_tanh(bf2f(v4.y) + qv.y);
            pp += wev.z * fast_tanh(bf2f(v4.z) + qv.z);
            pp += wev.w * fast_tanh(bf2f(v4.w) + qv.w);
            if (lane < 44) {
                int h = 256 + lane;
                pp += we_s[h] * fast_tanh(bf2f(row[h]) + q_s[h]);
            }
            #pragma unroll
            for (int off = 32; off; off >>= 1) pp += __shfl_xor(pp, off, 64);
            if (lane == 0) alpha[t] = pp;
        }
        __syncthreads();

        if (wv < 2) {
            float ev = alpha[tid];
            float m = ev;
            #pragma unroll
            for (int off = 32; off; off >>= 1) m = fmaxf(m, __shfl_xor(m, off, 64));
            if (lane == 0) red[wv] = m;
            __syncthreads();
            float gm = fmaxf(red[0], red[1]);
            float e = __expf(ev - gm);
            alpha[tid] = e;
            float s = e;
            #pragma unroll
            for (int off = 32; off; off >>= 1) s += __shfl_xor(s, off, 64);
            if (lane == 0) red[2 + wv] = s;
            __syncthreads();
            alpha[tid] *= 1.f / (red[2] + red[3]);
        } else {
            __syncthreads();
            __syncthreads();
        }
        __syncthreads();

        // PV
        {
            float a0 = 0.f, a1 = 0.f, a2 = 0.f, a3 = 0.f, at = 0.f;
            for (int t = wv; t < TPREM; t += 8) {
                float w = alpha[t];
                const unsigned short* row = hsb + (size_t)t * HDIM;
                ushort4 v4 = *reinterpret_cast<const ushort4*>(&row[4 * lane]);
                a0 = fmaf(w, bf2f(v4.x), a0);
                a1 = fmaf(w, bf2f(v4.y), a1);
                a2 = fmaf(w, bf2f(v4.z), a2);
                a3 = fmaf(w, bf2f(v4.w), a3);
                if (lane < 44) at = fmaf(w, bf2f(row[256 + lane]), at);
            }
            float4 av; av.x = a0; av.y = a1; av.z = a2; av.w = a3;
            *reinterpret_cast<float4*>(&U.pa[wv][4 * lane]) = av;
            if (lane < 44) U.pa[wv][256 + lane] = at;
            __syncthreads();
            for (int h = tid; h < HDIM; h += NTHR_D) {
                float s = 0.f;
                #pragma unroll
                for (int w8 = 0; w8 < 8; ++w8) s += U.pa[w8][h];
                gstore(&p.ab[(size_t)b * HDIM + h], s);
            }
        }
        arrive(cA);

        // cell (j<19): stage [ab | h_t] into LDS once, GEMM from LDS
        if (j < 19) {
            wait_ge(cA, 32u * (unsigned)(k + 1));
            const float* htp = p.h_t_all + (size_t)k * BH;
            for (int i2 = tid; i2 < 32 * HDIM; i2 += NTHR_D) {
                int r = i2 / HDIM, kk2 = i2 - r * HDIM;
                U.c.ab_s[r][kk2] = gload(&p.ab[(size_t)(b0 + r) * HDIM + kk2]);
                U.c.ht_s[r][kk2] = htp[(size_t)(b0 + r) * HDIM + kk2];
            }
            __syncthreads();

            const int fa_b = tid >> 4;
            const int fa_k0 = (tid & 15) * 2;
            const int fb_c = tid >> 3;
            const int fb_k0 = (tid & 7) * 4;
            const int hh_c = j * 16 + (fb_c >> 2);
            const int wrow = (fb_c & 3) * HDIM + hh_c;
            const bool wvalid = hh_c < HDIM;
            const int pb2 = tid & 15, cl = tid >> 4;
            float acc[2][2] = {};
            for (int kc = 0; kc < 608; kc += KTT) {
                #pragma unroll
                for (int u = 0; u < 2; ++u) {
                    int kk = fa_k0 + u, kg = kc + kk;
                    float v = 0.f;
                    if (kg < HDIM)      v = U.c.ab_s[fa_b][kg];
                    else if (kg < 600)  v = U.c.ht_s[fa_b][kg - HDIM];
                    As[kk][fa_b] = v;
                }
                #pragma unroll
                for (int u = 0; u < 4; ++u) {
                    int kk = fb_k0 + u, kg = kc + kk;
                    Bs[kk][fb_c] = (wvalid && kg < 600)
                        ? bf2f(mWihB[(size_t)wrow * 600 + kg]) : 0.f;
                }
                __syncthreads();
                #pragma unroll
                for (int kk = 0; kk < KTT; ++kk) {
                    float2 av2 = *(const float2*)&As[kk][pb2 * 2];
                    float2 wv2 = *(const float2*)&Bs[kk][cl * 2];
                    acc[0][0] = fmaf(av2.x, wv2.x, acc[0][0]);
                    acc[0][1] = fmaf(av2.x, wv2.y, acc[0][1]);
                    acc[1][0] = fmaf(av2.y, wv2.x, acc[1][0]);
                    acc[1][1] = fmaf(av2.y, wv2.y, acc[1][1]);
                }
                __syncthreads();
            }
            #pragma unroll
            for (int u = 0; u < 2; ++u)
                #pragma unroll
                for (int v = 0; v < 2; ++v)
                    gbuf[pb2 * 2 + u][cl * 2 + v] = acc[u][v];
            __syncthreads();
            {
                const int bl = tid & 31, hl2 = tid >> 5;
                int hh = j * 16 + hl2;
                if (hh < HDIM) {
                    float g0 = gbuf[bl][hl2 * 4 + 0];
                    float g2 = gbuf[bl][hl2 * 4 + 2];
                    float g3 = gbuf[bl][hl2 * 4 + 3];
                    float bi0 = p.mbih[hh] + p.mbhh[hh];
                    float bi2 = p.mbih[2 * HDIM + hh] + p.mbhh[2 * HDIM + hh];
                    float bi3 = p.mbih[3 * HDIM + hh] + p.mbhh[3 * HDIM + hh];
                    float gi = fast_sigm(g0 + bi0);
                    float gg = fast_tanh(g2 + bi2);
                    float go = fast_sigm(g3 + bi3);
                    gstore(&p.h_m[(size_t)(b0 + bl) * HDIM + hh],
                           go * fast_tanh(gi * gg));
                }
            }
            arrive(cC);
        }
    }

    // FC
    wait_ge(cC, 19u * (unsigned)THYP);
    float p0 = 0.f, p1 = 0.f, p2 = 0.f;
    for (int h = tid; h < HDIM; h += NTHR_D) {
        float v = gload(&p.h_m[(size_t)b * HDIM + h]);
        p0 = fmaf(v, p.fc_w[h], p0);
        p1 = fmaf(v, p.fc_w[HDIM + h], p1);
        p2 = fmaf(v, p.fc_w[2 * HDIM + h], p2);
    }
    #pragma unroll
    for (int off = 32; off; off >>= 1) {
        p0 += __shfl_xor(p0, off, 64);
        p1 += __shfl_xor(p1, off, 64);
        p2 += __shfl_xor(p2, off, 64);
    }
    __syncthreads();
    if (lane == 0) {
        red[wv * 3 + 0] = p0;
        red[wv * 3 + 1] = p1;
        red[wv * 3 + 2] = p2;
    }
    __syncthreads();
    if (tid == 0) {
        float o0 = 0.f, o1 = 0.f, o2 = 0.f;
        #pragma unroll
        for (int w8 = 0; w8 < 8; ++w8) {
            o0 += red[w8 * 3 + 0];
            o1 += red[w8 * 3 + 1];
            o2 += red[w8 * 3 + 2];
        }
        p.out[b * 3 + 0] = o0 + p.fc_b[0];
        p.out[b * 3 + 1] = o1 + p.fc_b[1];
        p.out[b * 3 + 2] = o2 + p.fc_b[2];
    }
}

// ===========================================================================
// Fallback path: round-1 multi-kernel implementation (proven correct).
// ===========================================================================
__global__ void k_lstm_gates(
    const int* __restrict__ tok, const float* __restrict__ w2v,
    const float* __restrict__ A0, int K0,
    const float* __restrict__ A1, int K1,
    const float* __restrict__ W0, int ld0,
    const float* __restrict__ W1, int ld1,
    const float* __restrict__ bih, const float* __restrict__ bhh,
    const float* __restrict__ c_in, float* __restrict__ c_out,
    float* __restrict__ h_out)
{
    constexpr int KT = 32;
    __shared__ __align__(16) float As[KT][34];
    __shared__ __align__(16) float Bs[KT][68];

    const int tid = threadIdx.x;
    const int b0 = blockIdx.x * 32;
    const int hh0 = blockIdx.y * 16;
    const int K = K0 + K1;
    const int pb = tid & 15;
    const int hl = tid >> 4;
    const int fa_b = tid >> 3;
    const int fa_k0 = (tid & 7) * 4;
    const int fb_c = tid >> 2;
    const int fb_k0 = (tid & 3) * 8;
    const int fb_hh = hh0 + (fb_c >> 2);
    const int fb_g = fb_c & 3;
    const int fb_row = fb_g * HDIM + fb_hh;
    const bool fb_valid = fb_hh < HDIM;
    const int ga = b0 + fa_b;
    const int tok_b = tok ? tok[ga] : 0;

    float acc[2][4] = {{0.f,0.f,0.f,0.f},{0.f,0.f,0.f,0.f}};

    for (int k0 = 0; k0 < K; k0 += KT) {
        #pragma unroll
        for (int u = 0; u < 4; ++u) {
            int kk = fa_k0 + u;
            int k = k0 + kk;
            float v = 0.f;
            if (k < K0)      v = tok ? w2v[(size_t)tok_b * K0 + k]
                                     : A0[(size_t)ga * K0 + k];
            else if (k < K)  v = A1[(size_t)ga * K1 + (k - K0)];
            As[kk][fa_b] = v;
        }
        #pragma unroll
        for (int u = 0; u < 8; ++u) {
            int kk = fb_k0 + u;
            int k = k0 + kk;
            float v = 0.f;
            if (fb_valid) {
                if (k < K0)     v = W0[(size_t)fb_row * ld0 + k];
                else if (k < K) v = W1[(size_t)fb_row * ld1 + (k - K0)];
            }
            Bs[kk][fb_c] = v;
        }
        __syncthreads();
        #pragma unroll
        for (int kk = 0; kk < KT; ++kk) {
            float2 av = *(const float2*)&As[kk][pb * 2];
            float4 wv = *(const float4*)&Bs[kk][hl * 4];
            acc[0][0] = fmaf(av.x, wv.x, acc[0][0]);
            acc[0][1] = fmaf(av.x, wv.y, acc[0][1]);
            acc[0][2] = fmaf(av.x, wv.z, acc[0][2]);
            acc[0][3] = fmaf(av.x, wv.w, acc[0][3]);
            acc[1][0] = fmaf(av.y, wv.x, acc[1][0]);
            acc[1][1] = fmaf(av.y, wv.y, acc[1][1]);
            acc[1][2] = fmaf(av.y, wv.z, acc[1][2]);
            acc[1][3] = fmaf(av.y, wv.w, acc[1][3]);
        }
        __syncthreads();
    }

    const int hh = hh0 + hl;
    if (hh < HDIM) {
        float bi = bih[hh] + bhh[hh];
        float bf = bih[HDIM + hh] + bhh[HDIM + hh];
        float bg = bih[2 * HDIM + hh] + bhh[2 * HDIM + hh];
        float bo = bih[3 * HDIM + hh] + bhh[3 * HDIM + hh];
        #pragma unroll
        for (int u = 0; u < 2; ++u) {
            int b = b0 + pb * 2 + u;
            float gi = fast_sigm(acc[u][0] + bi);
            float gf = fast_sigm(acc[u][1] + bf);
            float gg = fast_tanh(acc[u][2] + bg);
            float go = fast_sigm(acc[u][3] + bo);
            float c = gf * c_in[(size_t)b * HDIM + hh] + gi * gg;
            c_out[(size_t)b * HDIM + hh] = c;
            h_out[(size_t)b * HDIM + hh] = go * fast_tanh(c);
        }
    }
}

template<int BM, int BN, int TM, int TN, int KT>
__global__ void k_gemm_tn(
    const float* __restrict__ A0, int K0,
    const float* __restrict__ A1, int K1,
    const float* __restrict__ B0, int ldb0,
    const float* __restrict__ B1, int ldb1,
    float* __restrict__ C, int M, int N)
{
    __shared__ __align__(16) float As[KT][BM + 4];
    __shared__ __align__(16) float Bs[KT][BN + 4];
    const int tid = threadIdx.x;
    const int m0 = blockIdx.x * BM;
    const int n0 = blockIdx.y * BN;
    const int K = K0 + K1;
    constexpr int TPM = BM / TM;
    const int tm = tid % TPM;
    const int tn = tid / TPM;

    float acc[TM][TN];
    #pragma unroll
    for (int i = 0; i < TM; ++i)
        #pragma unroll
        for (int j = 0; j < TN; ++j) acc[i][j] = 0.f;

    for (int k0 = 0; k0 < K; k0 += KT) {
        for (int i = tid; i < KT * BM; i += 256) {
            int kk = i % KT, ml = i / KT;
            int m = m0 + ml, k = k0 + kk;
            float v = 0.f;
            if (m < M) {
                if (k < K0)     v = A0[(size_t)m * K0 + k];
                else if (k < K) v = A1[(size_t)m * K1 + (k - K0)];
            }
            As[kk][ml] = v;
        }
        for (int i = tid; i < KT * BN; i += 256) {
            int kk = i % KT, nl = i / KT;
            int n = n0 + nl, k = k0 + kk;
            float v = 0.f;
            if (n < N) {
                if (k < K0)     v = B0[(size_t)n * ldb0 + k];
                else if (k < K) v = B1[(size_t)n * ldb1 + (k - K0)];
            }
            Bs[kk][nl] = v;
        }
        __syncthreads();
        #pragma unroll
        for (int kk = 0; kk < KT; ++kk) {
            float a[TM], w[TN];
            #pragma unroll
            for (int i = 0; i < TM; ++i) a[i] = As[kk][tm * TM + i];
            #pragma unroll
            for (int j = 0; j < TN; ++j) w[j] = Bs[kk][tn * TN + j];
            #pragma unroll
            for (int i = 0; i < TM; ++i)
                #pragma unroll
                for (int j = 0; j < TN; ++j)
                    acc[i][j] = fmaf(a[i], w[j], acc[i][j]);
        }
        __syncthreads();
    }
    #pragma unroll
    for (int i = 0; i < TM; ++i) {
        int m = m0 + tm * TM + i;
        if (m >= M) continue;
        #pragma unroll
        for (int j = 0; j < TN; ++j) {
            int n = n0 + tn * TN + j;
            if (n < N) C[(size_t)m * N + n] = acc[i][j];
        }
    }
}

__global__ void k_attn(const float* __restrict__ ws_hs,
                       const float* __restrict__ h_s,
                       const float* __restrict__ q,
                       const float* __restrict__ w_e,
                       float* __restrict__ a_out)
{
    const int b = blockIdx.x;
    const int tid = threadIdx.x;
    const int lane = tid & 63;
    const int wv = tid >> 6;

    __shared__ float q_s[HDIM];
    __shared__ float we_s[HDIM];
    __shared__ float alpha[TPREM];
    __shared__ float red[4];

    for (int h = tid; h < HDIM; h += 256) {
        q_s[h] = q[(size_t)b * HDIM + h];
        we_s[h] = w_e[h];
    }
    __syncthreads();

    for (int t = wv; t < TPREM; t += 4) {
        const float* row = ws_hs + ((size_t)t * BATCH + b) * HDIM;
        float p = 0.f;
        for (int h = lane; h < HDIM; h += 64)
            p += we_s[h] * fast_tanh(row[h] + q_s[h]);
        #pragma unroll
        for (int off = 32; off; off >>= 1) p += __shfl_xor(p, off, 64);
        if (lane == 0) alpha[t] = p;
    }
    __syncthreads();

    if (wv < 2) {
        float ev = alpha[tid];
        float m = ev;
        #pragma unroll
        for (int off = 32; off; off >>= 1) m = fmaxf(m, __shfl_xor(m, off, 64));
        if (lane == 0) red[wv] = m;
        __syncthreads();
        float gm = fmaxf(red[0], red[1]);
        float e = __expf(ev - gm);
        alpha[tid] = e;
        float s = e;
        #pragma unroll
        for (int off = 32; off; off >>= 1) s += __shfl_xor(s, off, 64);
        if (lane == 0) red[2 + wv] = s;
        __syncthreads();
        alpha[tid] *= 1.f / (red[2] + red[3]);
    } else {
        __syncthreads();
        __syncthreads();
    }
    __syncthreads();

    for (int h = tid; h < HDIM; h += 256) {
        const float* hsb = h_s + (size_t)b * HDIM + h;
        float acc = 0.f;
        #pragma unroll 4
        for (int t = 0; t < TPREM; ++t)
            acc = fmaf(alpha[t], hsb[(size_t)t * BATCH * HDIM], acc);
        a_out[(size_t)b * HDIM + h] = acc;
    }
}

__global__ void k_fc(const float* __restrict__ h_m,
                     const float* __restrict__ fc_w,
                     const float* __restrict__ fc_b,
                     float* __restrict__ out)
{
    const int b = threadIdx.x;
    float a0 = 0.f, a1 = 0.f, a2 = 0.f;
    for (int h = 0; h < HDIM; ++h) {
        float v = h_m[(size_t)b * HDIM + h];
        a0 = fmaf(v, fc_w[h], a0);
        a1 = fmaf(v, fc_w[HDIM + h], a1);
        a2 = fmaf(v, fc_w[2 * HDIM + h], a2);
    }
    out[b * 3 + 0] = a0 + fc_b[0];
    out[b * 3 + 1] = a1 + fc_b[1];
    out[b * 3 + 2] = a2 + fc_b[2];
}

// ===========================================================================
extern "C" void kernel_launch(void* const* d_in, const int* in_sizes, int n_in,
                              void* d_out, int out_size, void* d_ws, size_t ws_size,
                              hipStream_t stream) {
    (void)in_sizes; (void)n_in; (void)out_size;
    const int*   premise    = (const int*)d_in[0];
    const int*   hypothesis = (const int*)d_in[2];
    const float* w2v        = (const float*)d_in[4];
    const float* w_e        = (const float*)d_in[5];
    const float* W_s        = (const float*)d_in[6];
    const float* W_t        = (const float*)d_in[7];
    const float* W_m        = (const float*)d_in[8];
    const float* fc_w       = (const float*)d_in[9];
    const float* fc_b       = (const float*)d_in[10];
    const float* pWih       = (const float*)d_in[11];
    const float* pWhh       = (const float*)d_in[12];
    const float* pbih       = (const float*)d_in[13];
    const float* pbhh       = (const float*)d_in[14];
    const float* hWih       = (const float*)d_in[15];
    const float* hWhh       = (const float*)d_in[16];
    const float* hbih       = (const float*)d_in[17];
    const float* hbhh       = (const float*)d_in[18];
    const float* mWih       = (const float*)d_in[19];
    const float* mbih       = (const float*)d_in[21];
    const float* mbhh       = (const float*)d_in[22];

    const size_t BH = (size_t)BATCH * HDIM;
    // ws: cnt 4096 + f32 194*BH + bf16 320*BH + wbuf (2.16M+64) bf16 ~= 113 MB
    const size_t NEED = 4096 + 194 * BH * 4 + 320 * BH * 2 + (WB_TOT + 64) * 2;

    if (ws_size >= NEED) {
        Params p;
        p.premise = premise; p.hypothesis = hypothesis;
        p.w2v = w2v; p.w_e = w_e;
        p.W_s = W_s; p.W_t = W_t; p.W_m = W_m;
        p.fc_w = fc_w; p.fc_b = fc_b;
        p.pWih = pWih; p.pWhh = pWhh; p.pbih = pbih; p.pbhh = pbhh;
        p.hWih = hWih; p.hWhh = hWhh; p.hbih = hbih; p.hbhh = hbhh;
        p.mWih = mWih; p.mbih = mbih; p.mbhh = mbhh;

        p.cnt = (unsigned*)d_ws;
        float* f = (float*)((char*)d_ws + 4096);
        p.h_s     = f; f += (size_t)TPREM * BH;
        p.h_t_all = f; f += (size_t)THYP * BH;
        p.h_m     = f; f += BH;
        p.ab      = f; f += BH;
        p.wshsT   = (unsigned short*)f;
        p.hsT     = p.wshsT + (size_t)TPREM * BH;
        p.wthtB   = p.hsT + (size_t)TPREM * BH;
        p.wbuf    = p.wthtB + (size_t)THYP * BH;
        p.out = (float*)d_out;

        k_init<<<2048, 256, 0, stream>>>(p);
        match_b<<<NBLK, NTHR, 0, stream>>>(p);
        k_proj<<<1536, NTHR, 0, stream>>>(p);
        match_d<<<BATCH, NTHR_D, 0, stream>>>(p);
        return;
    }

    // ---- fallback: round-1 multi-kernel path ----
    float* ws    = (float*)d_ws;
    float* h_s   = ws;
    float* wshs  = h_s + (size_t)TPREM * BH;
    float* zeros = wshs + (size_t)TPREM * BH;
    float* c_p   = zeros + BH;
    float* c_h   = c_p + BH;
    float* c_m   = c_h + BH;
    float* ht0   = c_m + BH;
    float* ht1   = ht0 + BH;
    float* h_m   = ht1 + BH;
    float* qb    = h_m + BH;
    float* ab    = qb + BH;

    (void)hipMemsetAsync(zeros, 0, BH * sizeof(float), stream);
    (void)hipMemsetAsync(c_p,   0, BH * sizeof(float), stream);
    (void)hipMemsetAsync(c_h,   0, BH * sizeof(float), stream);
    (void)hipMemsetAsync(h_m,   0, BH * sizeof(float), stream);

    dim3 gGate(BATCH / 32, (HDIM + 15) / 16);

    for (int t = 0; t < TPREM; ++t) {
        const float* hp = t ? (h_s + (size_t)(t - 1) * BH) : zeros;
        k_lstm_gates<<<gGate, 256, 0, stream>>>(
            premise + (size_t)t * BATCH, w2v, nullptr, EDIM,
            hp, HDIM, pWih, EDIM, pWhh, HDIM,
            pbih, pbhh, c_p, c_p, h_s + (size_t)t * BH);
    }

    k_gemm_tn<64, 64, 4, 4, 16><<<dim3(TPREM * BATCH / 64, (HDIM + 63) / 64), 256, 0, stream>>>(
        h_s, HDIM, nullptr, 0, W_s, HDIM, nullptr, 0, wshs, TPREM * BATCH, HDIM);

    for (int k = 0; k < THYP; ++k) {
        const float* hp = k ? ((k & 1) ? ht0 : ht1) : zeros;
        float* hc = (k & 1) ? ht1 : ht0;
        k_lstm_gates<<<gGate, 256, 0, stream>>>(
            hypothesis + (size_t)k * BATCH, w2v, nullptr, EDIM,
            hp, HDIM, hWih, EDIM, hWhh, HDIM,
            hbih, hbhh, c_h, c_h, hc);
        k_gemm_tn<16, 64, 1, 4, 16><<<dim3(BATCH / 16, (HDIM + 63) / 64), 256, 0, stream>>>(
            hc, HDIM, h_m, HDIM, W_t, HDIM, W_m, HDIM, qb, BATCH, HDIM);
        k_attn<<<BATCH, 256, 0, stream>>>(wshs, h_s, qb, w_e, ab);
        k_lstm_gates<<<gGate, 256, 0, stream>>>(
            nullptr, nullptr, ab, HDIM,
            hc, HDIM, mWih, 2 * HDIM, mWih + HDIM, 2 * HDIM,
            mbih, mbhh, zeros, c_m, h_m);
    }

    k_fc<<<1, BATCH, 0, stream>>>(h_m, fc_w, fc_b, (float*)d_out);
}